// Round 1
// 1378.593 us; speedup vs baseline: 1.1823x; 1.1823x over previous
//
#include <hip/hip_runtime.h>
#include <hip/hip_bf16.h>

// ---------------------------------------------------------------------------
// CorrectTransformerAdaptor — Round 5: m97-structure GEMM.
//   - One-shot cvt of all weights (+ per-chunk x) to a bf16 arena so GEMMs
//     are pure-bf16 and can use global_load_lds (width 16, direct-to-LDS).
//   - gemm_bf16: 128x128 tile, BK=64, 4 waves (2x2 of 64x64), XOR k-chunk
//     swizzle via pre-swizzled GLOBAL source (LDS dest linear, rule #21),
//     matching XOR on ds_read_b128 -> ~2-way (free) bank aliasing.
//   - attn_mfma / ln_wave / detect unchanged from round 4 (passing).
// ---------------------------------------------------------------------------

#define DMODEL 1024
#define DFF 2048
#define FHID 256
#define NHEAD 8
#define DKH 128
#define TSEQ 1024

typedef __hip_bfloat16 bf16;
typedef __attribute__((ext_vector_type(8))) short bf16x8;   // 8 bf16 = 4 VGPR
typedef __attribute__((ext_vector_type(4))) float f32x4;

#define MFMA16(a, b, c) __builtin_amdgcn_mfma_f32_16x16x32_bf16(a, b, c, 0, 0, 0)

__device__ int g_is_bf16;

__device__ __forceinline__ bool flagbf() {
    return __hip_atomic_load(&g_is_bf16, __ATOMIC_ACQUIRE,
                             __HIP_MEMORY_SCOPE_AGENT) != 0;
}
__device__ __forceinline__ float gload(const void* p, size_t i, bool bf) {
    return bf ? __bfloat162float(((const bf16*)p)[i]) : ((const float*)p)[i];
}
__device__ __forceinline__ void gstore(void* p, size_t i, bool bf, float v) {
    if (bf) ((bf16*)p)[i] = __float2bfloat16(v);
    else    ((float*)p)[i] = v;
}
// 16 consecutive elements -> bf16[16], vectorized for both dtypes.
__device__ __forceinline__ void load16(const void* p, size_t off, bool bf, bf16* dst) {
    if (bf) {
        const uint4* s = (const uint4*)((const bf16*)p + off);
        ((uint4*)dst)[0] = s[0];
        ((uint4*)dst)[1] = s[1];
    } else {
        const float4* s = (const float4*)((const float*)p + off);
        #pragma unroll
        for (int g = 0; g < 4; ++g) {
            float4 f = s[g];
            dst[g * 4 + 0] = __float2bfloat16(f.x);
            dst[g * 4 + 1] = __float2bfloat16(f.y);
            dst[g * 4 + 2] = __float2bfloat16(f.z);
            dst[g * 4 + 3] = __float2bfloat16(f.w);
        }
    }
}

// direct global->LDS, 16 bytes/lane. LDS base must be wave-uniform (m104);
// lane writes at base + lane*16. Global address is per-lane.
__device__ __forceinline__ void async16(const bf16* g, const bf16* l) {
    __builtin_amdgcn_global_load_lds(
        (const __attribute__((address_space(1))) void*)g,
        (__attribute__((address_space(3))) void*)l, 16, 0, 0);
}

// ---- dtype probe (64 lanes, ballot) ---------------------------------------
__global__ void detect_kernel(const void* __restrict__ probe) {
    const int lane = threadIdx.x & 63;
    const bf16* h = (const bf16*)probe;
    int ok = 1;
    #pragma unroll
    for (int j = 0; j < 4; ++j) {
        float v = __bfloat162float(h[lane * 4 + j]);
        if (!(fabsf(v) <= 1000.0f)) ok = 0;   // catches huge AND NaN
    }
    unsigned long long m = __ballot(ok);
    if (lane == 0)
        __hip_atomic_store(&g_is_bf16, m == ~0ull ? 1 : 0, __ATOMIC_RELEASE,
                           __HIP_MEMORY_SCOPE_AGENT);
}

// ---- weight arena offsets (bf16 elems) ------------------------------------
// W1 2048x1024 | W2 1024x2048 | Wq,Wk,Wv,Wo each 2x1024x1024 | Fw1,Fw2 2x256x1024
#define O_W1  0ull
#define O_W2  2097152ull
#define O_WQ  4194304ull
#define O_WK  6291456ull
#define O_WV  8388608ull
#define O_WO  10485760ull
#define O_F1  12582912ull
#define O_F2  13107200ull
#define ARENA_ELEMS 13631488ull

// one block = 4096 elems (256 thr x 16). all segment sizes divisible by 4096.
__global__ __launch_bounds__(256) void cvt_weights(
        const void* W1, const void* W2, const void* Wq, const void* Wk,
        const void* Wv, const void* Wo, const void* F1, const void* F2,
        bf16* __restrict__ arena) {
    const bool fl = flagbf();
    int b = blockIdx.x;
    const void* src; size_t base;
    if      (b < 512)  { src = W1; base = O_W1; }
    else if (b < 1024) { src = W2; base = O_W2; b -= 512;  }
    else if (b < 1536) { src = Wq; base = O_WQ; b -= 1024; }
    else if (b < 2048) { src = Wk; base = O_WK; b -= 1536; }
    else if (b < 2560) { src = Wv; base = O_WV; b -= 2048; }
    else if (b < 3072) { src = Wo; base = O_WO; b -= 2560; }
    else if (b < 3200) { src = F1; base = O_F1; b -= 3072; }
    else               { src = F2; base = O_F2; b -= 3200; }
    const size_t off = (size_t)b * 4096 + (size_t)threadIdx.x * 16;
    bf16 t[16];
    load16(src, off, fl, t);
    uint4* d = (uint4*)(arena + base + off);
    d[0] = ((uint4*)t)[0];
    d[1] = ((uint4*)t)[1];
}

__global__ __launch_bounds__(256) void cvt_x(
        const void* __restrict__ X, size_t x_off, bf16* __restrict__ dst) {
    const bool fl = flagbf();
    const size_t off = (size_t)blockIdx.x * 4096 + (size_t)threadIdx.x * 16;
    bf16 t[16];
    load16(X, x_off + off, fl, t);
    uint4* d = (uint4*)(dst + off);
    d[0] = ((uint4*)t)[0];
    d[1] = ((uint4*)t)[1];
}

// ---------------- m97-structure GEMM: C[M,N] = op(A[M,K] @ W[N,K]^T + b) ---
// A, W always bf16. CMODE: 0 = bf16 scratch C, 1 = flag-dtype harness buffer.
// 128x128 tile, BK=64, 4 waves in 2x2 grid of 64x64, acc 4x4 f32x4/wave.
// LDS linear [row][64], global source pre-swizzled: LDS(row,chunk) holds
// global k-chunk (chunk ^ (row&7)); ds_read applies the same XOR.
template <bool RELU, bool ADD, int CMODE>
__global__ __launch_bounds__(256) void gemm_bf16(
        const bf16* __restrict__ A,
        const bf16* __restrict__ W, size_t w_off,
        const void* __restrict__ bias, size_t b_off,
        void* __restrict__ C, size_t c_off,
        int M, int N, int K) {
    const bool fl = flagbf();

    __shared__ __align__(16) bf16 As[128 * 64];
    __shared__ __align__(16) bf16 Bs[128 * 64];

    const int bm = blockIdx.y * 128, bn = blockIdx.x * 128;
    const int tid = threadIdx.x;
    const int wave = tid >> 6, lane = tid & 63;
    const int quad = lane >> 4, l15 = lane & 15;
    const int wr = wave >> 1, wc = wave & 1;
    const int l8 = lane >> 3, l7 = lane & 7;
    const int swz = l7 ^ l8;          // row&7 == l8 for our staging rows

    const bf16* Wp = W + w_off;

    f32x4 acc[4][4];
    #pragma unroll
    for (int i = 0; i < 4; ++i)
        #pragma unroll
        for (int j = 0; j < 4; ++j) acc[i][j] = (f32x4){0.f, 0.f, 0.f, 0.f};

    // wave w stages rows [w*32, w*32+32) of both tiles; 4 issues of 8 rows.
    const bf16* ga0 = A  + (size_t)(bm + wave * 32 + l8) * K + swz * 8;
    const bf16* gb0 = Wp + (size_t)(bn + wave * 32 + l8) * K + swz * 8;
    bf16* la0 = &As[(wave * 32) * 64];
    bf16* lb0 = &Bs[(wave * 32) * 64];

    for (int k0 = 0; k0 < K; k0 += 64) {
        __syncthreads();                       // prev iter frag reads done
        #pragma unroll
        for (int i = 0; i < 4; ++i) {
            async16(ga0 + (size_t)(i * 8) * K + k0, la0 + i * 512);
            async16(gb0 + (size_t)(i * 8) * K + k0, lb0 + i * 512);
        }
        __syncthreads();                       // vmcnt drained by compiler

        #pragma unroll
        for (int ks = 0; ks < 2; ++ks) {
            bf16x8 af[4], bfr[4];
            #pragma unroll
            for (int mi = 0; mi < 4; ++mi) {
                const int row = wr * 64 + mi * 16 + l15;
                af[mi] = *(const bf16x8*)
                    &As[row * 64 + ((((ks << 2) | quad) ^ (row & 7)) << 3)];
            }
            #pragma unroll
            for (int ni = 0; ni < 4; ++ni) {
                const int row = wc * 64 + ni * 16 + l15;
                bfr[ni] = *(const bf16x8*)
                    &Bs[row * 64 + ((((ks << 2) | quad) ^ (row & 7)) << 3)];
            }
            #pragma unroll
            for (int mi = 0; mi < 4; ++mi)
                #pragma unroll
                for (int ni = 0; ni < 4; ++ni)
                    acc[mi][ni] = MFMA16(af[mi], bfr[ni], acc[mi][ni]);
        }
    }

    // epilogue: C row = quad*4+reg, col = lane&15 (verified m89/m91 layout)
    const bool cbf = CMODE ? fl : true;
    #pragma unroll
    for (int ni = 0; ni < 4; ++ni) {
        const int col = bn + wc * 64 + ni * 16 + l15;
        const float bv = gload(bias, b_off + col, fl);
        #pragma unroll
        for (int mi = 0; mi < 4; ++mi) {
            const int row0 = bm + wr * 64 + mi * 16 + quad * 4;
            #pragma unroll
            for (int rr = 0; rr < 4; ++rr) {
                float v = acc[mi][ni][rr] + bv;
                if (RELU) v = fmaxf(v, 0.f);
                size_t idx = c_off + (size_t)(row0 + rr) * N + col;
                if (ADD) v += gload(C, idx, cbf);
                gstore(C, idx, cbf, v);
            }
        }
    }
}

// ---------------- LayerNorm: one wave per row, shuffle-only ----------------
__global__ __launch_bounds__(256) void ln_wave(
        const void* __restrict__ X, size_t x_off,
        const void* __restrict__ g, const void* __restrict__ b, size_t gb_off,
        bf16* __restrict__ H) {
    const bool fl = flagbf();
    const int lane = threadIdx.x & 63;
    const int row = blockIdx.x * 4 + (threadIdx.x >> 6);
    const size_t xrow = x_off + (size_t)row * DMODEL;

    float v[16];
    if (fl) {
        const bf16* xp = (const bf16*)X + xrow;
        #pragma unroll
        for (int c = 0; c < 2; ++c) {
            uint4 raw = *(const uint4*)(xp + c * 512 + lane * 8);
            const bf16* rb = (const bf16*)&raw;
            #pragma unroll
            for (int j = 0; j < 8; ++j) v[c * 8 + j] = __bfloat162float(rb[j]);
        }
    } else {
        const float* xp = (const float*)X + xrow;
        #pragma unroll
        for (int c = 0; c < 4; ++c) {
            float4 f = *(const float4*)(xp + c * 256 + lane * 4);
            v[c * 4 + 0] = f.x; v[c * 4 + 1] = f.y;
            v[c * 4 + 2] = f.z; v[c * 4 + 3] = f.w;
        }
    }

    float s = 0.f;
    #pragma unroll
    for (int j = 0; j < 16; ++j) s += v[j];
    #pragma unroll
    for (int off = 32; off > 0; off >>= 1) s += __shfl_xor(s, off);
    const float mean = s * (1.f / DMODEL);

    float vs = 0.f;
    #pragma unroll
    for (int j = 0; j < 16; ++j) { float d = v[j] - mean; vs += d * d; }
    #pragma unroll
    for (int off = 32; off > 0; off >>= 1) vs += __shfl_xor(vs, off);
    const float rstd = rsqrtf(vs * (1.f / DMODEL) + 1e-12f);

    bf16* h = H + (size_t)row * DMODEL;
    if (fl) {
        const bf16* gp = (const bf16*)g + gb_off;
        const bf16* bp = (const bf16*)b + gb_off;
        #pragma unroll
        for (int c = 0; c < 2; ++c) {
            const int o = c * 512 + lane * 8;
            uint4 gr = *(const uint4*)(gp + o);
            uint4 br = *(const uint4*)(bp + o);
            const bf16* gg = (const bf16*)&gr;
            const bf16* bb = (const bf16*)&br;
            bf16 outv[8];
            #pragma unroll
            for (int j = 0; j < 8; ++j)
                outv[j] = __float2bfloat16((v[c * 8 + j] - mean) * rstd *
                          __bfloat162float(gg[j]) + __bfloat162float(bb[j]));
            *(uint4*)(h + o) = *(const uint4*)outv;
        }
    } else {
        const float* gp = (const float*)g + gb_off;
        const float* bp = (const float*)b + gb_off;
        #pragma unroll
        for (int c = 0; c < 4; ++c) {
            const int o = c * 256 + lane * 4;
            float4 gr = *(const float4*)(gp + o);
            float4 br = *(const float4*)(bp + o);
            const float gg[4] = {gr.x, gr.y, gr.z, gr.w};
            const float bb[4] = {br.x, br.y, br.z, br.w};
            bf16 outv[4];
            #pragma unroll
            for (int j = 0; j < 4; ++j)
                outv[j] = __float2bfloat16((v[c * 4 + j] - mean) * rstd * gg[j] + bb[j]);
            *(uint2*)(h + o) = *(const uint2*)outv;
        }
    }
}

// ---------------- Flash-style MFMA attention -------------------------------
// Grid: (TSEQ/64, NHEAD, c). Block: 256 threads = 4 waves, wave w owns
// q-rows [qt*64 + w*16, +16). K loop over 64-key tiles staged in LDS.
__global__ __launch_bounds__(256) void attn_mfma(
        const bf16* __restrict__ Qm, const bf16* __restrict__ Km,
        const bf16* __restrict__ Vm, bf16* __restrict__ Om) {
    const int qt = blockIdx.x, h = blockIdx.y, bb = blockIdx.z;
    const int tid = threadIdx.x;
    const int wave = tid >> 6, lane = tid & 63;
    const int quad = lane >> 4, l15 = lane & 15;

    __shared__ __align__(16) bf16 Kt[64][128];
    __shared__ __align__(16) bf16 Vt[128][64];
    __shared__ __align__(16) bf16 Ps[4][16][72];

    const size_t base = ((size_t)bb * TSEQ) * DMODEL + (size_t)h * DKH;
    const int qrow = qt * 64 + wave * 16 + l15;
    const float scale = 0.08838834764831845f;  // 1/sqrt(128)

    bf16x8 qf[4];
    #pragma unroll
    for (int kc = 0; kc < 4; ++kc) {
        uint4 raw = *(const uint4*)(Qm + base + (size_t)qrow * DMODEL + kc * 32 + quad * 8);
        const bf16* rb = (const bf16*)&raw;
        bf16 tmp[8];
        #pragma unroll
        for (int j = 0; j < 8; ++j)
            tmp[j] = __float2bfloat16(__bfloat162float(rb[j]) * scale);
        qf[kc] = *(const bf16x8*)tmp;
    }

    f32x4 o[8];
    #pragma unroll
    for (int i = 0; i < 8; ++i) o[i] = (f32x4){0.f, 0.f, 0.f, 0.f};
    float m_i[4] = {-1e30f, -1e30f, -1e30f, -1e30f};
    float l_i[4] = {0.f, 0.f, 0.f, 0.f};

    const int skey = tid >> 2;
    const int dseg = (tid & 3) * 32;
    const int skey3 = skey >> 3, sk7 = skey & 7;

    for (int kt = 0; kt < TSEQ / 64; ++kt) {
        __syncthreads();
        {
            const bf16* kp = Km + base + (size_t)(kt * 64 + skey) * DMODEL + dseg;
            const bf16* vp = Vm + base + (size_t)(kt * 64 + skey) * DMODEL + dseg;
            uint4 kv[4], vv[4];
            #pragma unroll
            for (int g = 0; g < 4; ++g) { kv[g] = ((const uint4*)kp)[g]; vv[g] = ((const uint4*)vp)[g]; }
            #pragma unroll
            for (int g = 0; g < 4; ++g) {
                int d3 = (dseg >> 3) + g;
                *(uint4*)&Kt[skey][(d3 ^ sk7) << 3] = kv[g];
            }
            const bf16* vsrc = (const bf16*)vv;
            #pragma unroll
            for (int j = 0; j < 32; ++j) {
                int d = dseg + j;
                Vt[d][((skey3 ^ (d & 7)) << 3) | sk7] = vsrc[j];
            }
        }
        __syncthreads();

        f32x4 s[4];
        #pragma unroll
        for (int ni = 0; ni < 4; ++ni) s[ni] = (f32x4){0.f, 0.f, 0.f, 0.f};
        #pragma unroll
        for (int ni = 0; ni < 4; ++ni) {
            const int key = ni * 16 + l15;
            #pragma unroll
            for (int kc = 0; kc < 4; ++kc) {
                const int d3 = kc * 4 + quad;
                bf16x8 kb = *(const bf16x8*)&Kt[key][(d3 ^ (key & 7)) << 3];
                s[ni] = MFMA16(qf[kc], kb, s[ni]);
            }
        }

        float tm[4], al[4], ts[4];
        #pragma unroll
        for (int rr = 0; rr < 4; ++rr) {
            float v = fmaxf(fmaxf(s[0][rr], s[1][rr]), fmaxf(s[2][rr], s[3][rr]));
            v = fmaxf(v, __shfl_xor(v, 1));
            v = fmaxf(v, __shfl_xor(v, 2));
            v = fmaxf(v, __shfl_xor(v, 4));
            v = fmaxf(v, __shfl_xor(v, 8));
            tm[rr] = v;
        }
        #pragma unroll
        for (int rr = 0; rr < 4; ++rr) {
            float mn = fmaxf(m_i[rr], tm[rr]);
            al[rr] = __expf(m_i[rr] - mn);
            m_i[rr] = mn;
            ts[rr] = 0.f;
        }
        #pragma unroll
        for (int ni = 0; ni < 4; ++ni)
            #pragma unroll
            for (int rr = 0; rr < 4; ++rr) {
                float p = __expf(s[ni][rr] - m_i[rr]);
                s[ni][rr] = p;
                ts[rr] += p;
            }
        #pragma unroll
        for (int rr = 0; rr < 4; ++rr) {
            float v = ts[rr];
            v += __shfl_xor(v, 1);
            v += __shfl_xor(v, 2);
            v += __shfl_xor(v, 4);
            v += __shfl_xor(v, 8);
            l_i[rr] = l_i[rr] * al[rr] + v;
        }
        #pragma unroll
        for (int i = 0; i < 8; ++i)
            #pragma unroll
            for (int rr = 0; rr < 4; ++rr) o[i][rr] *= al[rr];

        #pragma unroll
        for (int ni = 0; ni < 4; ++ni)
            #pragma unroll
            for (int rr = 0; rr < 4; ++rr)
                Ps[wave][quad * 4 + rr][ni * 16 + l15] = __float2bfloat16(s[ni][rr]);
        __asm__ __volatile__("s_waitcnt lgkmcnt(0)" ::: "memory");
        bf16x8 pa[2];
        #pragma unroll
        for (int kc2 = 0; kc2 < 2; ++kc2)
            pa[kc2] = *(const bf16x8*)&Ps[wave][l15][kc2 * 32 + quad * 8];

        #pragma unroll
        for (int ni2 = 0; ni2 < 8; ++ni2) {
            const int d = ni2 * 16 + l15;
            #pragma unroll
            for (int kc2 = 0; kc2 < 2; ++kc2) {
                const int key3 = kc2 * 4 + quad;
                bf16x8 vb = *(const bf16x8*)&Vt[d][(key3 ^ (d & 7)) << 3];
                o[ni2] = MFMA16(pa[kc2], vb, o[ni2]);
            }
        }
    }

    #pragma unroll
    for (int ni2 = 0; ni2 < 8; ++ni2)
        #pragma unroll
        for (int rr = 0; rr < 4; ++rr) {
            int qr = qt * 64 + wave * 16 + quad * 4 + rr;
            Om[base + (size_t)qr * DMODEL + ni2 * 16 + l15] =
                __float2bfloat16(o[ni2][rr] / l_i[rr]);
        }
}

// ---------------------------------------------------------------------------
extern "C" void kernel_launch(void* const* d_in, const int* in_sizes, int n_in,
                              void* d_out, int out_size, void* d_ws, size_t ws_size,
                              hipStream_t stream) {
    const void* x     = d_in[0];
    const void* W1    = d_in[1];
    const void* b1    = d_in[2];
    const void* W2    = d_in[3];
    const void* b2    = d_in[4];
    const void* ln1_g = d_in[5];
    const void* ln1_b = d_in[6];
    const void* ln2_g = d_in[7];
    const void* ln2_b = d_in[8];
    const void* Wq    = d_in[9];
    const void* bq    = d_in[10];
    const void* Wk    = d_in[11];
    const void* bk    = d_in[12];
    const void* Wv    = d_in[13];
    const void* bv    = d_in[14];
    const void* Wo    = d_in[15];
    const void* bo    = d_in[16];
    const void* Fw1   = d_in[17];
    const void* Fb1   = d_in[18];
    const void* Fw2   = d_in[19];
    const void* Fb2   = d_in[20];

    detect_kernel<<<1, 64, 0, stream>>>(W1);

    // workspace: [Hh | Qb | Kb | Vb | Xc | weight arena], all bf16
    int c = 8;
    while (c > 1 &&
           (5ull * (size_t)c * (1ull << 20) + ARENA_ELEMS) * 2ull > ws_size)
        c >>= 1;
    const int nch = 8 / c;
    const int Mc = c * TSEQ;
    const size_t SL = (size_t)Mc * DMODEL;

    bf16* Hh = (bf16*)d_ws;
    bf16* Qb = Hh + SL;
    bf16* Kb = Qb + SL;
    bf16* Vb = Kb + SL;
    bf16* Xc = Vb + SL;
    bf16* Wt = Xc + SL;
    bf16* Hid = Qb;   // Mc x 2048 spans Qb+Kb
    bf16* Ffh = Qb;   // Mc x 256
    bf16* Ob  = Hh;   // attn output reuses LN buffer
    void* X = d_out;  // residual stream (flag dtype)

    bf16* cW1 = Wt + O_W1;
    bf16* cW2 = Wt + O_W2;
    bf16* cWq = Wt + O_WQ;
    bf16* cWk = Wt + O_WK;
    bf16* cWv = Wt + O_WV;
    bf16* cWo = Wt + O_WO;
    bf16* cF1 = Wt + O_F1;
    bf16* cF2 = Wt + O_F2;

    cvt_weights<<<3328, 256, 0, stream>>>(W1, W2, Wq, Wk, Wv, Wo, Fw1, Fw2, Wt);

    for (int ci = 0; ci < nch; ++ci) {
        const size_t roff = (size_t)ci * Mc * DMODEL;

        cvt_x<<<(int)(SL / 4096), 256, 0, stream>>>(x, roff, Xc);

        gemm_bf16<true, false, 0><<<dim3(DFF / 128, Mc / 128), 256, 0, stream>>>(
            Xc, cW1, 0, b1, 0, Hid, 0, Mc, DFF, DMODEL);
        gemm_bf16<false, false, 1><<<dim3(DMODEL / 128, Mc / 128), 256, 0, stream>>>(
            Hid, cW2, 0, b2, 0, X, roff, Mc, DMODEL, DFF);

        for (int l = 0; l < 2; ++l) {
            const size_t wOff   = (size_t)l * DMODEL * DMODEL;
            const size_t vOff   = (size_t)l * DMODEL;
            const size_t f1wOff = (size_t)l * FHID * DMODEL;
            const size_t f1bOff = (size_t)l * FHID;

            ln_wave<<<Mc / 4, 256, 0, stream>>>(X, roff, ln1_g, ln1_b, vOff, Hh);
            gemm_bf16<false, false, 0><<<dim3(DMODEL / 128, Mc / 128), 256, 0, stream>>>(
                Hh, cWq, wOff, bq, vOff, Qb, 0, Mc, DMODEL, DMODEL);
            gemm_bf16<false, false, 0><<<dim3(DMODEL / 128, Mc / 128), 256, 0, stream>>>(
                Hh, cWk, wOff, bk, vOff, Kb, 0, Mc, DMODEL, DMODEL);
            gemm_bf16<false, false, 0><<<dim3(DMODEL / 128, Mc / 128), 256, 0, stream>>>(
                Hh, cWv, wOff, bv, vOff, Vb, 0, Mc, DMODEL, DMODEL);

            attn_mfma<<<dim3(TSEQ / 64, NHEAD, c), 256, 0, stream>>>(Qb, Kb, Vb, Ob);

            gemm_bf16<false, true, 1><<<dim3(DMODEL / 128, Mc / 128), 256, 0, stream>>>(
                Ob, cWo, wOff, bo, vOff, X, roff, Mc, DMODEL, DMODEL);

            ln_wave<<<Mc / 4, 256, 0, stream>>>(X, roff, ln2_g, ln2_b, vOff, Hh);
            gemm_bf16<true, false, 0><<<dim3(FHID / 128, Mc / 128), 256, 0, stream>>>(
                Hh, cF1, f1wOff, Fb1, f1bOff, Ffh, 0, Mc, FHID, DMODEL);
            gemm_bf16<false, true, 1><<<dim3(DMODEL / 128, Mc / 128), 256, 0, stream>>>(
                Ffh, cF2, f1wOff, Fb2, vOff, X, roff, Mc, DMODEL, FHID);
        }
    }
}

// Round 2
// 1332.472 us; speedup vs baseline: 1.2232x; 1.0346x over previous
//
#include <hip/hip_runtime.h>
#include <hip/hip_bf16.h>

// ---------------------------------------------------------------------------
// CorrectTransformerAdaptor — Round 6: kill attn V-transpose staging.
//   - V GEMM now stores V^T [1024][Mc] directly from the accumulator
//     (TRANSC epilogue, packed uint2 stores). Attention V staging becomes
//     vectorized uint4 + ds_write_b128 (was 32 scalar ds_write_b16 → 19.4M
//     bank conflicts). LDS read pattern unchanged (already conflict-free).
//   - Q,K GEMMs merged into one N=2048 launch (arena: Wq[l]||Wk[l]),
//     block-uniform bias select; attn reads QK buffer with stride 2048.
//   - gemm core / ln_wave / detect unchanged.
// ---------------------------------------------------------------------------

#define DMODEL 1024
#define DFF 2048
#define FHID 256
#define NHEAD 8
#define DKH 128
#define TSEQ 1024

typedef __hip_bfloat16 bf16;
typedef __attribute__((ext_vector_type(8))) short bf16x8;   // 8 bf16 = 4 VGPR
typedef __attribute__((ext_vector_type(4))) float f32x4;

#define MFMA16(a, b, c) __builtin_amdgcn_mfma_f32_16x16x32_bf16(a, b, c, 0, 0, 0)

__device__ int g_is_bf16;

__device__ __forceinline__ bool flagbf() {
    return __hip_atomic_load(&g_is_bf16, __ATOMIC_ACQUIRE,
                             __HIP_MEMORY_SCOPE_AGENT) != 0;
}
__device__ __forceinline__ float gload(const void* p, size_t i, bool bf) {
    return bf ? __bfloat162float(((const bf16*)p)[i]) : ((const float*)p)[i];
}
__device__ __forceinline__ void gstore(void* p, size_t i, bool bf, float v) {
    if (bf) ((bf16*)p)[i] = __float2bfloat16(v);
    else    ((float*)p)[i] = v;
}
// 16 consecutive elements -> bf16[16], vectorized for both dtypes.
__device__ __forceinline__ void load16(const void* p, size_t off, bool bf, bf16* dst) {
    if (bf) {
        const uint4* s = (const uint4*)((const bf16*)p + off);
        ((uint4*)dst)[0] = s[0];
        ((uint4*)dst)[1] = s[1];
    } else {
        const float4* s = (const float4*)((const float*)p + off);
        #pragma unroll
        for (int g = 0; g < 4; ++g) {
            float4 f = s[g];
            dst[g * 4 + 0] = __float2bfloat16(f.x);
            dst[g * 4 + 1] = __float2bfloat16(f.y);
            dst[g * 4 + 2] = __float2bfloat16(f.z);
            dst[g * 4 + 3] = __float2bfloat16(f.w);
        }
    }
}

// direct global->LDS, 16 bytes/lane. LDS base must be wave-uniform (m104);
// lane writes at base + lane*16. Global address is per-lane.
__device__ __forceinline__ void async16(const bf16* g, const bf16* l) {
    __builtin_amdgcn_global_load_lds(
        (const __attribute__((address_space(1))) void*)g,
        (__attribute__((address_space(3))) void*)l, 16, 0, 0);
}

// ---- dtype probe (64 lanes, ballot) ---------------------------------------
__global__ void detect_kernel(const void* __restrict__ probe) {
    const int lane = threadIdx.x & 63;
    const bf16* h = (const bf16*)probe;
    int ok = 1;
    #pragma unroll
    for (int j = 0; j < 4; ++j) {
        float v = __bfloat162float(h[lane * 4 + j]);
        if (!(fabsf(v) <= 1000.0f)) ok = 0;   // catches huge AND NaN
    }
    unsigned long long m = __ballot(ok);
    if (lane == 0)
        __hip_atomic_store(&g_is_bf16, m == ~0ull ? 1 : 0, __ATOMIC_RELEASE,
                           __HIP_MEMORY_SCOPE_AGENT);
}

// ---- weight arena offsets (bf16 elems) ------------------------------------
// W1 2M | W2 2M | QK: per-layer [Wq;Wk] 2M each (4M) | Wv 2M | Wo 2M | F1 .5M | F2 .5M
#define O_W1  0ull
#define O_W2  2097152ull
#define O_QK  4194304ull
#define O_WV  8388608ull
#define O_WO  10485760ull
#define O_F1  12582912ull
#define O_F2  13107200ull
#define ARENA_ELEMS 13631488ull

// one block = 4096 elems (256 thr x 16). all segment sizes divisible by 4096.
__global__ __launch_bounds__(256) void cvt_weights(
        const void* W1, const void* W2, const void* Wq, const void* Wk,
        const void* Wv, const void* Wo, const void* F1, const void* F2,
        bf16* __restrict__ arena) {
    const bool fl = flagbf();
    int b = blockIdx.x;
    const void* src; size_t sbase; size_t dbase;
    if      (b < 512)  { src = W1; sbase = (size_t)b * 4096; dbase = O_W1 + sbase; }
    else if (b < 1024) { b -= 512;  src = W2; sbase = (size_t)b * 4096; dbase = O_W2 + sbase; }
    else if (b < 1536) { b -= 1024; src = Wq; sbase = (size_t)b * 4096;
                         dbase = O_QK + (size_t)(b >> 8) * 2097152 + (size_t)(b & 255) * 4096; }
    else if (b < 2048) { b -= 1536; src = Wk; sbase = (size_t)b * 4096;
                         dbase = O_QK + (size_t)(b >> 8) * 2097152 + 1048576 + (size_t)(b & 255) * 4096; }
    else if (b < 2560) { b -= 2048; src = Wv; sbase = (size_t)b * 4096; dbase = O_WV + sbase; }
    else if (b < 3072) { b -= 2560; src = Wo; sbase = (size_t)b * 4096; dbase = O_WO + sbase; }
    else if (b < 3200) { b -= 3072; src = F1; sbase = (size_t)b * 4096; dbase = O_F1 + sbase; }
    else               { b -= 3200; src = F2; sbase = (size_t)b * 4096; dbase = O_F2 + sbase; }
    const size_t t16 = (size_t)threadIdx.x * 16;
    bf16 t[16];
    load16(src, sbase + t16, fl, t);
    uint4* d = (uint4*)(arena + dbase + t16);
    d[0] = ((uint4*)t)[0];
    d[1] = ((uint4*)t)[1];
}

__global__ __launch_bounds__(256) void cvt_x(
        const void* __restrict__ X, size_t x_off, bf16* __restrict__ dst) {
    const bool fl = flagbf();
    const size_t off = (size_t)blockIdx.x * 4096 + (size_t)threadIdx.x * 16;
    bf16 t[16];
    load16(X, x_off + off, fl, t);
    uint4* d = (uint4*)(dst + off);
    d[0] = ((uint4*)t)[0];
    d[1] = ((uint4*)t)[1];
}

// ---------------- m97-structure GEMM: C[M,N] = op(A[M,K] @ W[N,K]^T + b) ---
// A, W always bf16. CMODE: 0 = bf16 scratch C, 1 = flag-dtype harness buffer.
// TRANSC: store C^T (bf16) at C[col*M + row] — used to produce V^T.
// BIAS2: two-way bias select at col 1024 (merged QK GEMM, block-uniform).
template <bool RELU, bool ADD, int CMODE, bool TRANSC, bool BIAS2>
__global__ __launch_bounds__(256) void gemm_bf16(
        const bf16* __restrict__ A,
        const bf16* __restrict__ W, size_t w_off,
        const void* __restrict__ bias, const void* __restrict__ bias2,
        size_t b_off,
        void* __restrict__ C, size_t c_off,
        int M, int N, int K) {
    const bool fl = flagbf();

    __shared__ __align__(16) bf16 As[128 * 64];
    __shared__ __align__(16) bf16 Bs[128 * 64];

    const int bm = blockIdx.y * 128, bn = blockIdx.x * 128;
    const int tid = threadIdx.x;
    const int wave = tid >> 6, lane = tid & 63;
    const int quad = lane >> 4, l15 = lane & 15;
    const int wr = wave >> 1, wc = wave & 1;
    const int l8 = lane >> 3, l7 = lane & 7;
    const int swz = l7 ^ l8;          // row&7 == l8 for our staging rows

    const bf16* Wp = W + w_off;

    f32x4 acc[4][4];
    #pragma unroll
    for (int i = 0; i < 4; ++i)
        #pragma unroll
        for (int j = 0; j < 4; ++j) acc[i][j] = (f32x4){0.f, 0.f, 0.f, 0.f};

    // wave w stages rows [w*32, w*32+32) of both tiles; 4 issues of 8 rows.
    const bf16* ga0 = A  + (size_t)(bm + wave * 32 + l8) * K + swz * 8;
    const bf16* gb0 = Wp + (size_t)(bn + wave * 32 + l8) * K + swz * 8;
    bf16* la0 = &As[(wave * 32) * 64];
    bf16* lb0 = &Bs[(wave * 32) * 64];

    for (int k0 = 0; k0 < K; k0 += 64) {
        __syncthreads();                       // prev iter frag reads done
        #pragma unroll
        for (int i = 0; i < 4; ++i) {
            async16(ga0 + (size_t)(i * 8) * K + k0, la0 + i * 512);
            async16(gb0 + (size_t)(i * 8) * K + k0, lb0 + i * 512);
        }
        __syncthreads();                       // vmcnt drained by compiler

        #pragma unroll
        for (int ks = 0; ks < 2; ++ks) {
            bf16x8 af[4], bfr[4];
            #pragma unroll
            for (int mi = 0; mi < 4; ++mi) {
                const int row = wr * 64 + mi * 16 + l15;
                af[mi] = *(const bf16x8*)
                    &As[row * 64 + ((((ks << 2) | quad) ^ (row & 7)) << 3)];
            }
            #pragma unroll
            for (int ni = 0; ni < 4; ++ni) {
                const int row = wc * 64 + ni * 16 + l15;
                bfr[ni] = *(const bf16x8*)
                    &Bs[row * 64 + ((((ks << 2) | quad) ^ (row & 7)) << 3)];
            }
            #pragma unroll
            for (int mi = 0; mi < 4; ++mi)
                #pragma unroll
                for (int ni = 0; ni < 4; ++ni)
                    acc[mi][ni] = MFMA16(af[mi], bfr[ni], acc[mi][ni]);
        }
    }

    // epilogue: acc row = quad*4+rr, col = lane&15 (verified m89/m91 layout)
    const bool cbf = CMODE ? fl : true;
    #pragma unroll
    for (int ni = 0; ni < 4; ++ni) {
        const int col = bn + wc * 64 + ni * 16 + l15;
        float bv;
        if (BIAS2) bv = col < 1024 ? gload(bias, b_off + col, fl)
                                   : gload(bias2, b_off + col - 1024, fl);
        else       bv = gload(bias, b_off + col, fl);
        #pragma unroll
        for (int mi = 0; mi < 4; ++mi) {
            const int row0 = bm + wr * 64 + mi * 16 + quad * 4;
            if (TRANSC) {
                bf16 pk[4];
                #pragma unroll
                for (int rr = 0; rr < 4; ++rr)
                    pk[rr] = __float2bfloat16(acc[mi][ni][rr] + bv);
                *(uint2*)((bf16*)C + c_off + (size_t)col * M + row0) =
                    *(const uint2*)pk;
            } else {
                #pragma unroll
                for (int rr = 0; rr < 4; ++rr) {
                    float v = acc[mi][ni][rr] + bv;
                    if (RELU) v = fmaxf(v, 0.f);
                    size_t idx = c_off + (size_t)(row0 + rr) * N + col;
                    if (ADD) v += gload(C, idx, cbf);
                    gstore(C, idx, cbf, v);
                }
            }
        }
    }
}

// ---------------- LayerNorm: one wave per row, shuffle-only ----------------
__global__ __launch_bounds__(256) void ln_wave(
        const void* __restrict__ X, size_t x_off,
        const void* __restrict__ g, const void* __restrict__ b, size_t gb_off,
        bf16* __restrict__ H) {
    const bool fl = flagbf();
    const int lane = threadIdx.x & 63;
    const int row = blockIdx.x * 4 + (threadIdx.x >> 6);
    const size_t xrow = x_off + (size_t)row * DMODEL;

    float v[16];
    if (fl) {
        const bf16* xp = (const bf16*)X + xrow;
        #pragma unroll
        for (int c = 0; c < 2; ++c) {
            uint4 raw = *(const uint4*)(xp + c * 512 + lane * 8);
            const bf16* rb = (const bf16*)&raw;
            #pragma unroll
            for (int j = 0; j < 8; ++j) v[c * 8 + j] = __bfloat162float(rb[j]);
        }
    } else {
        const float* xp = (const float*)X + xrow;
        #pragma unroll
        for (int c = 0; c < 4; ++c) {
            float4 f = *(const float4*)(xp + c * 256 + lane * 4);
            v[c * 4 + 0] = f.x; v[c * 4 + 1] = f.y;
            v[c * 4 + 2] = f.z; v[c * 4 + 3] = f.w;
        }
    }

    float s = 0.f;
    #pragma unroll
    for (int j = 0; j < 16; ++j) s += v[j];
    #pragma unroll
    for (int off = 32; off > 0; off >>= 1) s += __shfl_xor(s, off);
    const float mean = s * (1.f / DMODEL);

    float vs = 0.f;
    #pragma unroll
    for (int j = 0; j < 16; ++j) { float d = v[j] - mean; vs += d * d; }
    #pragma unroll
    for (int off = 32; off > 0; off >>= 1) vs += __shfl_xor(vs, off);
    const float rstd = rsqrtf(vs * (1.f / DMODEL) + 1e-12f);

    bf16* h = H + (size_t)row * DMODEL;
    if (fl) {
        const bf16* gp = (const bf16*)g + gb_off;
        const bf16* bp = (const bf16*)b + gb_off;
        #pragma unroll
        for (int c = 0; c < 2; ++c) {
            const int o = c * 512 + lane * 8;
            uint4 gr = *(const uint4*)(gp + o);
            uint4 br = *(const uint4*)(bp + o);
            const bf16* gg = (const bf16*)&gr;
            const bf16* bb = (const bf16*)&br;
            bf16 outv[8];
            #pragma unroll
            for (int j = 0; j < 8; ++j)
                outv[j] = __float2bfloat16((v[c * 8 + j] - mean) * rstd *
                          __bfloat162float(gg[j]) + __bfloat162float(bb[j]));
            *(uint4*)(h + o) = *(const uint4*)outv;
        }
    } else {
        const float* gp = (const float*)g + gb_off;
        const float* bp = (const float*)b + gb_off;
        #pragma unroll
        for (int c = 0; c < 4; ++c) {
            const int o = c * 256 + lane * 4;
            float4 gr = *(const float4*)(gp + o);
            float4 br = *(const float4*)(bp + o);
            const float gg[4] = {gr.x, gr.y, gr.z, gr.w};
            const float bb[4] = {br.x, br.y, br.z, br.w};
            bf16 outv[4];
            #pragma unroll
            for (int j = 0; j < 4; ++j)
                outv[j] = __float2bfloat16((v[c * 4 + j] - mean) * rstd * gg[j] + bb[j]);
            *(uint2*)(h + o) = *(const uint2*)outv;
        }
    }
}

// ---------------- Flash-style MFMA attention -------------------------------
// Grid: (TSEQ/64, NHEAD, c). Block: 256 threads = 4 waves, wave w owns
// q-rows [qt*64 + w*16, +16). K loop over 64-key tiles staged in LDS.
// QK: fused [Mc][2048] buffer (Q at col h*128, K at col 1024+h*128).
// Vg: V^T [1024][Mc] — staging is vectorized row loads (no transpose).
__global__ __launch_bounds__(256) void attn_mfma(
        const bf16* __restrict__ QK, const bf16* __restrict__ Vg,
        bf16* __restrict__ Om) {
    const int qt = blockIdx.x, h = blockIdx.y, bb = blockIdx.z;
    const int Mc = (int)gridDim.z * TSEQ;
    const int tid = threadIdx.x;
    const int wave = tid >> 6, lane = tid & 63;
    const int quad = lane >> 4, l15 = lane & 15;

    __shared__ __align__(16) bf16 Kt[64][128];
    __shared__ __align__(16) bf16 Vt[128][64];
    __shared__ __align__(16) bf16 Ps[4][16][72];

    const int qrow = qt * 64 + wave * 16 + l15;
    const float scale = 0.08838834764831845f;  // 1/sqrt(128)

    bf16x8 qf[4];
    #pragma unroll
    for (int kc = 0; kc < 4; ++kc) {
        uint4 raw = *(const uint4*)(QK + (size_t)(bb * TSEQ + qrow) * 2048 +
                                    h * DKH + kc * 32 + quad * 8);
        const bf16* rb = (const bf16*)&raw;
        bf16 tmp[8];
        #pragma unroll
        for (int j = 0; j < 8; ++j)
            tmp[j] = __float2bfloat16(__bfloat162float(rb[j]) * scale);
        qf[kc] = *(const bf16x8*)tmp;
    }

    f32x4 o[8];
    #pragma unroll
    for (int i = 0; i < 8; ++i) o[i] = (f32x4){0.f, 0.f, 0.f, 0.f};
    float m_i[4] = {-1e30f, -1e30f, -1e30f, -1e30f};
    float l_i[4] = {0.f, 0.f, 0.f, 0.f};

    const int skey = tid >> 2;              // K staging: row = key
    const int dseg = (tid & 3) * 32;
    const int sk7 = skey & 7;
    const int vd = tid >> 1;                // V staging: row = d
    const int vseg = (tid & 1) * 32;

    for (int kt = 0; kt < TSEQ / 64; ++kt) {
        __syncthreads();
        {
            const bf16* kp = QK + (size_t)(bb * TSEQ + kt * 64 + skey) * 2048 +
                             1024 + h * DKH + dseg;
            const bf16* vp = Vg + (size_t)(h * DKH + vd) * Mc + bb * TSEQ +
                             kt * 64 + vseg;
            uint4 kv[4], vv[4];
            #pragma unroll
            for (int g = 0; g < 4; ++g) { kv[g] = ((const uint4*)kp)[g]; vv[g] = ((const uint4*)vp)[g]; }
            #pragma unroll
            for (int g = 0; g < 4; ++g) {
                int d3 = (dseg >> 3) + g;
                *(uint4*)&Kt[skey][(d3 ^ sk7) << 3] = kv[g];
            }
            #pragma unroll
            for (int g = 0; g < 4; ++g) {
                int c = (vseg >> 3) + g;
                *(uint4*)&Vt[vd][(c ^ (vd & 7)) << 3] = vv[g];
            }
        }
        __syncthreads();

        f32x4 s[4];
        #pragma unroll
        for (int ni = 0; ni < 4; ++ni) s[ni] = (f32x4){0.f, 0.f, 0.f, 0.f};
        #pragma unroll
        for (int ni = 0; ni < 4; ++ni) {
            const int key = ni * 16 + l15;
            #pragma unroll
            for (int kc = 0; kc < 4; ++kc) {
                const int d3 = kc * 4 + quad;
                bf16x8 kb = *(const bf16x8*)&Kt[key][(d3 ^ (key & 7)) << 3];
                s[ni] = MFMA16(qf[kc], kb, s[ni]);
            }
        }

        float tm[4], al[4], ts[4];
        #pragma unroll
        for (int rr = 0; rr < 4; ++rr) {
            float v = fmaxf(fmaxf(s[0][rr], s[1][rr]), fmaxf(s[2][rr], s[3][rr]));
            v = fmaxf(v, __shfl_xor(v, 1));
            v = fmaxf(v, __shfl_xor(v, 2));
            v = fmaxf(v, __shfl_xor(v, 4));
            v = fmaxf(v, __shfl_xor(v, 8));
            tm[rr] = v;
        }
        #pragma unroll
        for (int rr = 0; rr < 4; ++rr) {
            float mn = fmaxf(m_i[rr], tm[rr]);
            al[rr] = __expf(m_i[rr] - mn);
            m_i[rr] = mn;
            ts[rr] = 0.f;
        }
        #pragma unroll
        for (int ni = 0; ni < 4; ++ni)
            #pragma unroll
            for (int rr = 0; rr < 4; ++rr) {
                float p = __expf(s[ni][rr] - m_i[rr]);
                s[ni][rr] = p;
                ts[rr] += p;
            }
        #pragma unroll
        for (int rr = 0; rr < 4; ++rr) {
            float v = ts[rr];
            v += __shfl_xor(v, 1);
            v += __shfl_xor(v, 2);
            v += __shfl_xor(v, 4);
            v += __shfl_xor(v, 8);
            l_i[rr] = l_i[rr] * al[rr] + v;
        }
        #pragma unroll
        for (int i = 0; i < 8; ++i)
            #pragma unroll
            for (int rr = 0; rr < 4; ++rr) o[i][rr] *= al[rr];

        #pragma unroll
        for (int ni = 0; ni < 4; ++ni)
            #pragma unroll
            for (int rr = 0; rr < 4; ++rr)
                Ps[wave][quad * 4 + rr][ni * 16 + l15] = __float2bfloat16(s[ni][rr]);
        __asm__ __volatile__("s_waitcnt lgkmcnt(0)" ::: "memory");
        bf16x8 pa[2];
        #pragma unroll
        for (int kc2 = 0; kc2 < 2; ++kc2)
            pa[kc2] = *(const bf16x8*)&Ps[wave][l15][kc2 * 32 + quad * 8];

        #pragma unroll
        for (int ni2 = 0; ni2 < 8; ++ni2) {
            const int d = ni2 * 16 + l15;
            #pragma unroll
            for (int kc2 = 0; kc2 < 2; ++kc2) {
                const int key3 = kc2 * 4 + quad;
                bf16x8 vb = *(const bf16x8*)&Vt[d][(key3 ^ (d & 7)) << 3];
                o[ni2] = MFMA16(pa[kc2], vb, o[ni2]);
            }
        }
    }

    const size_t obase = (size_t)bb * TSEQ * DMODEL + (size_t)h * DKH;
    #pragma unroll
    for (int ni2 = 0; ni2 < 8; ++ni2)
        #pragma unroll
        for (int rr = 0; rr < 4; ++rr) {
            int qr = qt * 64 + wave * 16 + quad * 4 + rr;
            Om[obase + (size_t)qr * DMODEL + ni2 * 16 + l15] =
                __float2bfloat16(o[ni2][rr] / l_i[rr]);
        }
}

// ---------------------------------------------------------------------------
extern "C" void kernel_launch(void* const* d_in, const int* in_sizes, int n_in,
                              void* d_out, int out_size, void* d_ws, size_t ws_size,
                              hipStream_t stream) {
    const void* x     = d_in[0];
    const void* W1    = d_in[1];
    const void* b1    = d_in[2];
    const void* W2    = d_in[3];
    const void* b2    = d_in[4];
    const void* ln1_g = d_in[5];
    const void* ln1_b = d_in[6];
    const void* ln2_g = d_in[7];
    const void* ln2_b = d_in[8];
    const void* Wq    = d_in[9];
    const void* bq    = d_in[10];
    const void* Wk    = d_in[11];
    const void* bk    = d_in[12];
    const void* Wv    = d_in[13];
    const void* bv    = d_in[14];
    const void* Wo    = d_in[15];
    const void* bo    = d_in[16];
    const void* Fw1   = d_in[17];
    const void* Fb1   = d_in[18];
    const void* Fw2   = d_in[19];
    const void* Fb2   = d_in[20];

    detect_kernel<<<1, 64, 0, stream>>>(W1);

    // workspace: [Hh | QKb | Vtb | Xc | weight arena], all bf16
    int c = 8;
    while (c > 1 &&
           (5ull * (size_t)c * (1ull << 20) + ARENA_ELEMS) * 2ull > ws_size)
        c >>= 1;
    const int nch = 8 / c;
    const int Mc = c * TSEQ;
    const size_t SL = (size_t)Mc * DMODEL;

    bf16* Hh  = (bf16*)d_ws;      // Mc x 1024
    bf16* QKb = Hh + SL;          // Mc x 2048 (fused Q|K)
    bf16* Vtb = QKb + 2 * SL;     // 1024 x Mc (V^T)
    bf16* Xc  = Vtb + SL;         // Mc x 1024
    bf16* Wt  = Xc + SL;          // weight arena
    bf16* Hid = QKb;              // Mc x 2048 scratch (downsample hidden)
    bf16* Ffh = QKb;              // Mc x 256 scratch (FFN hidden)
    bf16* Ob  = Hh;               // attn output reuses LN buffer
    void* X = d_out;              // residual stream (flag dtype)

    bf16* cW1  = Wt + O_W1;
    bf16* cW2  = Wt + O_W2;
    bf16* cWqk = Wt + O_QK;
    bf16* cWv  = Wt + O_WV;
    bf16* cWo  = Wt + O_WO;
    bf16* cF1  = Wt + O_F1;
    bf16* cF2  = Wt + O_F2;

    cvt_weights<<<3328, 256, 0, stream>>>(W1, W2, Wq, Wk, Wv, Wo, Fw1, Fw2, Wt);

    for (int ci = 0; ci < nch; ++ci) {
        const size_t roff = (size_t)ci * Mc * DMODEL;

        cvt_x<<<(int)(SL / 4096), 256, 0, stream>>>(x, roff, Xc);

        gemm_bf16<true, false, 0, false, false><<<dim3(DFF / 128, Mc / 128), 256, 0, stream>>>(
            Xc, cW1, 0, b1, nullptr, 0, Hid, 0, Mc, DFF, DMODEL);
        gemm_bf16<false, false, 1, false, false><<<dim3(DMODEL / 128, Mc / 128), 256, 0, stream>>>(
            Hid, cW2, 0, b2, nullptr, 0, X, roff, Mc, DMODEL, DFF);

        for (int l = 0; l < 2; ++l) {
            const size_t wOff   = (size_t)l * DMODEL * DMODEL;
            const size_t qkOff  = (size_t)l * 2ull * DMODEL * DMODEL;
            const size_t vOff   = (size_t)l * DMODEL;
            const size_t f1wOff = (size_t)l * FHID * DMODEL;
            const size_t f1bOff = (size_t)l * FHID;

            ln_wave<<<Mc / 4, 256, 0, stream>>>(X, roff, ln1_g, ln1_b, vOff, Hh);
            // fused Q|K GEMM: N=2048, bias select at col 1024 (block-uniform)
            gemm_bf16<false, false, 0, false, true><<<dim3(2048 / 128, Mc / 128), 256, 0, stream>>>(
                Hh, cWqk, qkOff, bq, bk, vOff, QKb, 0, Mc, 2048, DMODEL);
            // V GEMM with transposed store -> Vtb = V^T [1024][Mc]
            gemm_bf16<false, false, 0, true, false><<<dim3(DMODEL / 128, Mc / 128), 256, 0, stream>>>(
                Hh, cWv, wOff, bv, nullptr, vOff, Vtb, 0, Mc, DMODEL, DMODEL);

            attn_mfma<<<dim3(TSEQ / 64, NHEAD, c), 256, 0, stream>>>(QKb, Vtb, Ob);

            gemm_bf16<false, true, 1, false, false><<<dim3(DMODEL / 128, Mc / 128), 256, 0, stream>>>(
                Ob, cWo, wOff, bo, nullptr, vOff, X, roff, Mc, DMODEL, DMODEL);

            ln_wave<<<Mc / 4, 256, 0, stream>>>(X, roff, ln2_g, ln2_b, vOff, Hh);
            gemm_bf16<true, false, 0, false, false><<<dim3(FHID / 128, Mc / 128), 256, 0, stream>>>(
                Hh, cF1, f1wOff, Fb1, nullptr, f1bOff, Ffh, 0, Mc, FHID, DMODEL);
            gemm_bf16<false, true, 1, false, false><<<dim3(DMODEL / 128, Mc / 128), 256, 0, stream>>>(
                Ffh, cF2, f1wOff, Fb2, nullptr, vOff, X, roff, Mc, DMODEL, FHID);
        }
    }
}

// Round 3
// 1331.964 us; speedup vs baseline: 1.2237x; 1.0004x over previous
//
#include <hip/hip_runtime.h>
#include <hip/hip_bf16.h>

// ---------------------------------------------------------------------------
// CorrectTransformerAdaptor — Round 7: skip dtype conversion when bf16.
//   - rocprof showed cvt_weights = 109 µs/launch (top dispatch), FETCH 26.6MB
//     == bf16 weight footprint => harness inputs ARE bf16 => arena copy is an
//     identity copy (pure waste).
//   - cvt_weights / cvt_x now early-exit when flag==bf16. Every GEMM takes
//     both candidate pointers (original input vs converted arena, offsets
//     folded host-side) and selects on the device flag. fp32 path unchanged.
//   - QK fused GEMM takes (W_lo, W_hi) pairs since original Wq/Wk are not
//     adjacent buffers.
//   - gemm core / attn / ln_wave sync structure untouched.
// ---------------------------------------------------------------------------

#define DMODEL 1024
#define DFF 2048
#define FHID 256
#define NHEAD 8
#define DKH 128
#define TSEQ 1024

typedef __hip_bfloat16 bf16;
typedef __attribute__((ext_vector_type(8))) short bf16x8;   // 8 bf16 = 4 VGPR
typedef __attribute__((ext_vector_type(4))) float f32x4;

#define MFMA16(a, b, c) __builtin_amdgcn_mfma_f32_16x16x32_bf16(a, b, c, 0, 0, 0)

__device__ int g_is_bf16;

__device__ __forceinline__ bool flagbf() {
    return __hip_atomic_load(&g_is_bf16, __ATOMIC_ACQUIRE,
                             __HIP_MEMORY_SCOPE_AGENT) != 0;
}
__device__ __forceinline__ float gload(const void* p, size_t i, bool bf) {
    return bf ? __bfloat162float(((const bf16*)p)[i]) : ((const float*)p)[i];
}
__device__ __forceinline__ void gstore(void* p, size_t i, bool bf, float v) {
    if (bf) ((bf16*)p)[i] = __float2bfloat16(v);
    else    ((float*)p)[i] = v;
}
// 16 consecutive elements -> bf16[16], vectorized for both dtypes.
__device__ __forceinline__ void load16(const void* p, size_t off, bool bf, bf16* dst) {
    if (bf) {
        const uint4* s = (const uint4*)((const bf16*)p + off);
        ((uint4*)dst)[0] = s[0];
        ((uint4*)dst)[1] = s[1];
    } else {
        const float4* s = (const float4*)((const float*)p + off);
        #pragma unroll
        for (int g = 0; g < 4; ++g) {
            float4 f = s[g];
            dst[g * 4 + 0] = __float2bfloat16(f.x);
            dst[g * 4 + 1] = __float2bfloat16(f.y);
            dst[g * 4 + 2] = __float2bfloat16(f.z);
            dst[g * 4 + 3] = __float2bfloat16(f.w);
        }
    }
}

// direct global->LDS, 16 bytes/lane. LDS base must be wave-uniform (m104);
// lane writes at base + lane*16. Global address is per-lane.
__device__ __forceinline__ void async16(const bf16* g, const bf16* l) {
    __builtin_amdgcn_global_load_lds(
        (const __attribute__((address_space(1))) void*)g,
        (__attribute__((address_space(3))) void*)l, 16, 0, 0);
}

// ---- dtype probe (64 lanes, ballot) ---------------------------------------
__global__ void detect_kernel(const void* __restrict__ probe) {
    const int lane = threadIdx.x & 63;
    const bf16* h = (const bf16*)probe;
    int ok = 1;
    #pragma unroll
    for (int j = 0; j < 4; ++j) {
        float v = __bfloat162float(h[lane * 4 + j]);
        if (!(fabsf(v) <= 1000.0f)) ok = 0;   // catches huge AND NaN
    }
    unsigned long long m = __ballot(ok);
    if (lane == 0)
        __hip_atomic_store(&g_is_bf16, m == ~0ull ? 1 : 0, __ATOMIC_RELEASE,
                           __HIP_MEMORY_SCOPE_AGENT);
}

// ---- weight arena offsets (bf16 elems) — fp32-input path only -------------
#define O_W1  0ull
#define O_W2  2097152ull
#define O_QK  4194304ull
#define O_WV  8388608ull
#define O_WO  10485760ull
#define O_F1  12582912ull
#define O_F2  13107200ull
#define ARENA_ELEMS 13631488ull

// one block = 4096 elems (256 thr x 16). all segment sizes divisible by 4096.
__global__ __launch_bounds__(256) void cvt_weights(
        const void* W1, const void* W2, const void* Wq, const void* Wk,
        const void* Wv, const void* Wo, const void* F1, const void* F2,
        bf16* __restrict__ arena) {
    if (flagbf()) return;      // inputs already bf16: GEMMs read them directly
    int b = blockIdx.x;
    const void* src; size_t sbase; size_t dbase;
    if      (b < 512)  { src = W1; sbase = (size_t)b * 4096; dbase = O_W1 + sbase; }
    else if (b < 1024) { b -= 512;  src = W2; sbase = (size_t)b * 4096; dbase = O_W2 + sbase; }
    else if (b < 1536) { b -= 1024; src = Wq; sbase = (size_t)b * 4096;
                         dbase = O_QK + (size_t)(b >> 8) * 2097152 + (size_t)(b & 255) * 4096; }
    else if (b < 2048) { b -= 1536; src = Wk; sbase = (size_t)b * 4096;
                         dbase = O_QK + (size_t)(b >> 8) * 2097152 + 1048576 + (size_t)(b & 255) * 4096; }
    else if (b < 2560) { b -= 2048; src = Wv; sbase = (size_t)b * 4096; dbase = O_WV + sbase; }
    else if (b < 3072) { b -= 2560; src = Wo; sbase = (size_t)b * 4096; dbase = O_WO + sbase; }
    else if (b < 3200) { b -= 3072; src = F1; sbase = (size_t)b * 4096; dbase = O_F1 + sbase; }
    else               { b -= 3200; src = F2; sbase = (size_t)b * 4096; dbase = O_F2 + sbase; }
    const size_t t16 = (size_t)threadIdx.x * 16;
    bf16 t[16];
    load16(src, sbase + t16, false, t);
    uint4* d = (uint4*)(arena + dbase + t16);
    d[0] = ((uint4*)t)[0];
    d[1] = ((uint4*)t)[1];
}

__global__ __launch_bounds__(256) void cvt_x(
        const void* __restrict__ X, size_t x_off, bf16* __restrict__ dst) {
    if (flagbf()) return;      // bf16 x is consumed in place
    const size_t off = (size_t)blockIdx.x * 4096 + (size_t)threadIdx.x * 16;
    bf16 t[16];
    load16(X, x_off + off, false, t);
    uint4* d = (uint4*)(dst + off);
    d[0] = ((uint4*)t)[0];
    d[1] = ((uint4*)t)[1];
}

// ---------------- m97-structure GEMM: C[M,N] = op(A[M,K] @ W[N,K]^T + b) ---
// Operand pointers come in (bf16-direct, converted-arena) pairs, selected on
// the device dtype flag; all row offsets folded host-side.
// CMODE: 0 = bf16 scratch C, 1 = flag-dtype harness buffer.
// TRANSC: store C^T (bf16) at C[col*M + row] — used to produce V^T.
// BIAS2: two-way weight/bias select at col 1024 (merged QK GEMM, uniform).
template <bool RELU, bool ADD, int CMODE, bool TRANSC, bool BIAS2>
__global__ __launch_bounds__(256) void gemm_bf16(
        const bf16* Abf, const bf16* Acv,
        const bf16* Wlo_bf, const bf16* Whi_bf,
        const bf16* Wlo_cv, const bf16* Whi_cv,
        const void* __restrict__ bias, const void* __restrict__ bias2,
        size_t b_off,
        void* __restrict__ C, size_t c_off,
        int M, int N, int K) {
    const bool fl = flagbf();
    const bf16* A   = fl ? Abf : Acv;
    const bf16* Wlo = fl ? Wlo_bf : Wlo_cv;
    const bf16* Whi = fl ? Whi_bf : Whi_cv;

    __shared__ __align__(16) bf16 As[128 * 64];
    __shared__ __align__(16) bf16 Bs[128 * 64];

    const int bm = blockIdx.y * 128, bn = blockIdx.x * 128;
    const int tid = threadIdx.x;
    const int wave = tid >> 6, lane = tid & 63;
    const int quad = lane >> 4, l15 = lane & 15;
    const int wr = wave >> 1, wc = wave & 1;
    const int l8 = lane >> 3, l7 = lane & 7;
    const int swz = l7 ^ l8;          // row&7 == l8 for our staging rows

    const bf16* Wp;
    int bnr;
    if (BIAS2 && bn >= 1024) { Wp = Whi; bnr = bn - 1024; }
    else                     { Wp = Wlo; bnr = bn; }

    f32x4 acc[4][4];
    #pragma unroll
    for (int i = 0; i < 4; ++i)
        #pragma unroll
        for (int j = 0; j < 4; ++j) acc[i][j] = (f32x4){0.f, 0.f, 0.f, 0.f};

    // wave w stages rows [w*32, w*32+32) of both tiles; 4 issues of 8 rows.
    const bf16* ga0 = A  + (size_t)(bm  + wave * 32 + l8) * K + swz * 8;
    const bf16* gb0 = Wp + (size_t)(bnr + wave * 32 + l8) * K + swz * 8;
    bf16* la0 = &As[(wave * 32) * 64];
    bf16* lb0 = &Bs[(wave * 32) * 64];

    for (int k0 = 0; k0 < K; k0 += 64) {
        __syncthreads();                       // prev iter frag reads done
        #pragma unroll
        for (int i = 0; i < 4; ++i) {
            async16(ga0 + (size_t)(i * 8) * K + k0, la0 + i * 512);
            async16(gb0 + (size_t)(i * 8) * K + k0, lb0 + i * 512);
        }
        __syncthreads();                       // vmcnt drained by compiler

        #pragma unroll
        for (int ks = 0; ks < 2; ++ks) {
            bf16x8 af[4], bfr[4];
            #pragma unroll
            for (int mi = 0; mi < 4; ++mi) {
                const int row = wr * 64 + mi * 16 + l15;
                af[mi] = *(const bf16x8*)
                    &As[row * 64 + ((((ks << 2) | quad) ^ (row & 7)) << 3)];
            }
            #pragma unroll
            for (int ni = 0; ni < 4; ++ni) {
                const int row = wc * 64 + ni * 16 + l15;
                bfr[ni] = *(const bf16x8*)
                    &Bs[row * 64 + ((((ks << 2) | quad) ^ (row & 7)) << 3)];
            }
            #pragma unroll
            for (int mi = 0; mi < 4; ++mi)
                #pragma unroll
                for (int ni = 0; ni < 4; ++ni)
                    acc[mi][ni] = MFMA16(af[mi], bfr[ni], acc[mi][ni]);
        }
    }

    // epilogue: acc row = quad*4+rr, col = lane&15 (verified m89/m91 layout)
    const bool cbf = CMODE ? fl : true;
    #pragma unroll
    for (int ni = 0; ni < 4; ++ni) {
        const int col = bn + wc * 64 + ni * 16 + l15;
        float bv;
        if (BIAS2) bv = col < 1024 ? gload(bias, b_off + col, fl)
                                   : gload(bias2, b_off + col - 1024, fl);
        else       bv = gload(bias, b_off + col, fl);
        #pragma unroll
        for (int mi = 0; mi < 4; ++mi) {
            const int row0 = bm + wr * 64 + mi * 16 + quad * 4;
            if (TRANSC) {
                bf16 pk[4];
                #pragma unroll
                for (int rr = 0; rr < 4; ++rr)
                    pk[rr] = __float2bfloat16(acc[mi][ni][rr] + bv);
                *(uint2*)((bf16*)C + c_off + (size_t)col * M + row0) =
                    *(const uint2*)pk;
            } else {
                #pragma unroll
                for (int rr = 0; rr < 4; ++rr) {
                    float v = acc[mi][ni][rr] + bv;
                    if (RELU) v = fmaxf(v, 0.f);
                    size_t idx = c_off + (size_t)(row0 + rr) * N + col;
                    if (ADD) v += gload(C, idx, cbf);
                    gstore(C, idx, cbf, v);
                }
            }
        }
    }
}

// ---------------- LayerNorm: one wave per row, shuffle-only ----------------
__global__ __launch_bounds__(256) void ln_wave(
        const void* __restrict__ X, size_t x_off,
        const void* __restrict__ g, const void* __restrict__ b, size_t gb_off,
        bf16* __restrict__ H) {
    const bool fl = flagbf();
    const int lane = threadIdx.x & 63;
    const int row = blockIdx.x * 4 + (threadIdx.x >> 6);
    const size_t xrow = x_off + (size_t)row * DMODEL;

    float v[16];
    if (fl) {
        const bf16* xp = (const bf16*)X + xrow;
        #pragma unroll
        for (int c = 0; c < 2; ++c) {
            uint4 raw = *(const uint4*)(xp + c * 512 + lane * 8);
            const bf16* rb = (const bf16*)&raw;
            #pragma unroll
            for (int j = 0; j < 8; ++j) v[c * 8 + j] = __bfloat162float(rb[j]);
        }
    } else {
        const float* xp = (const float*)X + xrow;
        #pragma unroll
        for (int c = 0; c < 4; ++c) {
            float4 f = *(const float4*)(xp + c * 256 + lane * 4);
            v[c * 4 + 0] = f.x; v[c * 4 + 1] = f.y;
            v[c * 4 + 2] = f.z; v[c * 4 + 3] = f.w;
        }
    }

    float s = 0.f;
    #pragma unroll
    for (int j = 0; j < 16; ++j) s += v[j];
    #pragma unroll
    for (int off = 32; off > 0; off >>= 1) s += __shfl_xor(s, off);
    const float mean = s * (1.f / DMODEL);

    float vs = 0.f;
    #pragma unroll
    for (int j = 0; j < 16; ++j) { float d = v[j] - mean; vs += d * d; }
    #pragma unroll
    for (int off = 32; off > 0; off >>= 1) vs += __shfl_xor(vs, off);
    const float rstd = rsqrtf(vs * (1.f / DMODEL) + 1e-12f);

    bf16* h = H + (size_t)row * DMODEL;
    if (fl) {
        const bf16* gp = (const bf16*)g + gb_off;
        const bf16* bp = (const bf16*)b + gb_off;
        #pragma unroll
        for (int c = 0; c < 2; ++c) {
            const int o = c * 512 + lane * 8;
            uint4 gr = *(const uint4*)(gp + o);
            uint4 br = *(const uint4*)(bp + o);
            const bf16* gg = (const bf16*)&gr;
            const bf16* bb = (const bf16*)&br;
            bf16 outv[8];
            #pragma unroll
            for (int j = 0; j < 8; ++j)
                outv[j] = __float2bfloat16((v[c * 8 + j] - mean) * rstd *
                          __bfloat162float(gg[j]) + __bfloat162float(bb[j]));
            *(uint4*)(h + o) = *(const uint4*)outv;
        }
    } else {
        const float* gp = (const float*)g + gb_off;
        const float* bp = (const float*)b + gb_off;
        #pragma unroll
        for (int c = 0; c < 4; ++c) {
            const int o = c * 256 + lane * 4;
            float4 gr = *(const float4*)(gp + o);
            float4 br = *(const float4*)(bp + o);
            const float gg[4] = {gr.x, gr.y, gr.z, gr.w};
            const float bb[4] = {br.x, br.y, br.z, br.w};
            bf16 outv[4];
            #pragma unroll
            for (int j = 0; j < 4; ++j)
                outv[j] = __float2bfloat16((v[c * 4 + j] - mean) * rstd * gg[j] + bb[j]);
            *(uint2*)(h + o) = *(const uint2*)outv;
        }
    }
}

// ---------------- Flash-style MFMA attention -------------------------------
// Grid: (TSEQ/64, NHEAD, c). Block: 256 threads = 4 waves, wave w owns
// q-rows [qt*64 + w*16, +16). K loop over 64-key tiles staged in LDS.
// QK: fused [Mc][2048] buffer (Q at col h*128, K at col 1024+h*128).
// Vg: V^T [1024][Mc] — staging is vectorized row loads (no transpose).
__global__ __launch_bounds__(256) void attn_mfma(
        const bf16* __restrict__ QK, const bf16* __restrict__ Vg,
        bf16* __restrict__ Om) {
    const int qt = blockIdx.x, h = blockIdx.y, bb = blockIdx.z;
    const int Mc = (int)gridDim.z * TSEQ;
    const int tid = threadIdx.x;
    const int wave = tid >> 6, lane = tid & 63;
    const int quad = lane >> 4, l15 = lane & 15;

    __shared__ __align__(16) bf16 Kt[64][128];
    __shared__ __align__(16) bf16 Vt[128][64];
    __shared__ __align__(16) bf16 Ps[4][16][72];

    const int qrow = qt * 64 + wave * 16 + l15;
    const float scale = 0.08838834764831845f;  // 1/sqrt(128)

    bf16x8 qf[4];
    #pragma unroll
    for (int kc = 0; kc < 4; ++kc) {
        uint4 raw = *(const uint4*)(QK + (size_t)(bb * TSEQ + qrow) * 2048 +
                                    h * DKH + kc * 32 + quad * 8);
        const bf16* rb = (const bf16*)&raw;
        bf16 tmp[8];
        #pragma unroll
        for (int j = 0; j < 8; ++j)
            tmp[j] = __float2bfloat16(__bfloat162float(rb[j]) * scale);
        qf[kc] = *(const bf16x8*)tmp;
    }

    f32x4 o[8];
    #pragma unroll
    for (int i = 0; i < 8; ++i) o[i] = (f32x4){0.f, 0.f, 0.f, 0.f};
    float m_i[4] = {-1e30f, -1e30f, -1e30f, -1e30f};
    float l_i[4] = {0.f, 0.f, 0.f, 0.f};

    const int skey = tid >> 2;              // K staging: row = key
    const int dseg = (tid & 3) * 32;
    const int sk7 = skey & 7;
    const int vd = tid >> 1;                // V staging: row = d
    const int vseg = (tid & 1) * 32;

    for (int kt = 0; kt < TSEQ / 64; ++kt) {
        __syncthreads();
        {
            const bf16* kp = QK + (size_t)(bb * TSEQ + kt * 64 + skey) * 2048 +
                             1024 + h * DKH + dseg;
            const bf16* vp = Vg + (size_t)(h * DKH + vd) * Mc + bb * TSEQ +
                             kt * 64 + vseg;
            uint4 kv[4], vv[4];
            #pragma unroll
            for (int g = 0; g < 4; ++g) { kv[g] = ((const uint4*)kp)[g]; vv[g] = ((const uint4*)vp)[g]; }
            #pragma unroll
            for (int g = 0; g < 4; ++g) {
                int d3 = (dseg >> 3) + g;
                *(uint4*)&Kt[skey][(d3 ^ sk7) << 3] = kv[g];
            }
            #pragma unroll
            for (int g = 0; g < 4; ++g) {
                int c = (vseg >> 3) + g;
                *(uint4*)&Vt[vd][(c ^ (vd & 7)) << 3] = vv[g];
            }
        }
        __syncthreads();

        f32x4 s[4];
        #pragma unroll
        for (int ni = 0; ni < 4; ++ni) s[ni] = (f32x4){0.f, 0.f, 0.f, 0.f};
        #pragma unroll
        for (int ni = 0; ni < 4; ++ni) {
            const int key = ni * 16 + l15;
            #pragma unroll
            for (int kc = 0; kc < 4; ++kc) {
                const int d3 = kc * 4 + quad;
                bf16x8 kb = *(const bf16x8*)&Kt[key][(d3 ^ (key & 7)) << 3];
                s[ni] = MFMA16(qf[kc], kb, s[ni]);
            }
        }

        float tm[4], al[4], ts[4];
        #pragma unroll
        for (int rr = 0; rr < 4; ++rr) {
            float v = fmaxf(fmaxf(s[0][rr], s[1][rr]), fmaxf(s[2][rr], s[3][rr]));
            v = fmaxf(v, __shfl_xor(v, 1));
            v = fmaxf(v, __shfl_xor(v, 2));
            v = fmaxf(v, __shfl_xor(v, 4));
            v = fmaxf(v, __shfl_xor(v, 8));
            tm[rr] = v;
        }
        #pragma unroll
        for (int rr = 0; rr < 4; ++rr) {
            float mn = fmaxf(m_i[rr], tm[rr]);
            al[rr] = __expf(m_i[rr] - mn);
            m_i[rr] = mn;
            ts[rr] = 0.f;
        }
        #pragma unroll
        for (int ni = 0; ni < 4; ++ni)
            #pragma unroll
            for (int rr = 0; rr < 4; ++rr) {
                float p = __expf(s[ni][rr] - m_i[rr]);
                s[ni][rr] = p;
                ts[rr] += p;
            }
        #pragma unroll
        for (int rr = 0; rr < 4; ++rr) {
            float v = ts[rr];
            v += __shfl_xor(v, 1);
            v += __shfl_xor(v, 2);
            v += __shfl_xor(v, 4);
            v += __shfl_xor(v, 8);
            l_i[rr] = l_i[rr] * al[rr] + v;
        }
        #pragma unroll
        for (int i = 0; i < 8; ++i)
            #pragma unroll
            for (int rr = 0; rr < 4; ++rr) o[i][rr] *= al[rr];

        #pragma unroll
        for (int ni = 0; ni < 4; ++ni)
            #pragma unroll
            for (int rr = 0; rr < 4; ++rr)
                Ps[wave][quad * 4 + rr][ni * 16 + l15] = __float2bfloat16(s[ni][rr]);
        __asm__ __volatile__("s_waitcnt lgkmcnt(0)" ::: "memory");
        bf16x8 pa[2];
        #pragma unroll
        for (int kc2 = 0; kc2 < 2; ++kc2)
            pa[kc2] = *(const bf16x8*)&Ps[wave][l15][kc2 * 32 + quad * 8];

        #pragma unroll
        for (int ni2 = 0; ni2 < 8; ++ni2) {
            const int d = ni2 * 16 + l15;
            #pragma unroll
            for (int kc2 = 0; kc2 < 2; ++kc2) {
                const int key3 = kc2 * 4 + quad;
                bf16x8 vb = *(const bf16x8*)&Vt[d][(key3 ^ (d & 7)) << 3];
                o[ni2] = MFMA16(pa[kc2], vb, o[ni2]);
            }
        }
    }

    const size_t obase = (size_t)bb * TSEQ * DMODEL + (size_t)h * DKH;
    #pragma unroll
    for (int ni2 = 0; ni2 < 8; ++ni2)
        #pragma unroll
        for (int rr = 0; rr < 4; ++rr) {
            int qr = qt * 64 + wave * 16 + quad * 4 + rr;
            Om[obase + (size_t)qr * DMODEL + ni2 * 16 + l15] =
                __float2bfloat16(o[ni2][rr] / l_i[rr]);
        }
}

// ---------------------------------------------------------------------------
extern "C" void kernel_launch(void* const* d_in, const int* in_sizes, int n_in,
                              void* d_out, int out_size, void* d_ws, size_t ws_size,
                              hipStream_t stream) {
    const void* x     = d_in[0];
    const void* W1    = d_in[1];
    const void* b1    = d_in[2];
    const void* W2    = d_in[3];
    const void* b2    = d_in[4];
    const void* ln1_g = d_in[5];
    const void* ln1_b = d_in[6];
    const void* ln2_g = d_in[7];
    const void* ln2_b = d_in[8];
    const void* Wq    = d_in[9];
    const void* bq    = d_in[10];
    const void* Wk    = d_in[11];
    const void* bk    = d_in[12];
    const void* Wv    = d_in[13];
    const void* bv    = d_in[14];
    const void* Wo    = d_in[15];
    const void* bo    = d_in[16];
    const void* Fw1   = d_in[17];
    const void* Fb1   = d_in[18];
    const void* Fw2   = d_in[19];
    const void* Fb2   = d_in[20];

    detect_kernel<<<1, 64, 0, stream>>>(W1);

    // workspace: [Hh | QKb | Vtb | Xc | weight arena], all bf16
    int c = 8;
    while (c > 1 &&
           (5ull * (size_t)c * (1ull << 20) + ARENA_ELEMS) * 2ull > ws_size)
        c >>= 1;
    const int nch = 8 / c;
    const int Mc = c * TSEQ;
    const size_t SL = (size_t)Mc * DMODEL;

    bf16* Hh  = (bf16*)d_ws;      // Mc x 1024
    bf16* QKb = Hh + SL;          // Mc x 2048 (fused Q|K)
    bf16* Vtb = QKb + 2 * SL;     // 1024 x Mc (V^T)
    bf16* Xc  = Vtb + SL;         // Mc x 1024 (fp32-input path only)
    bf16* Wt  = Xc + SL;          // weight arena (fp32-input path only)
    bf16* Hid = QKb;              // Mc x 2048 scratch (downsample hidden)
    bf16* Ffh = QKb;              // Mc x 256 scratch (FFN hidden)
    bf16* Ob  = Hh;               // attn output reuses LN buffer
    void* X = d_out;              // residual stream (flag dtype)

    const bf16* xb  = (const bf16*)x;
    bf16* cW1  = Wt + O_W1;
    bf16* cW2  = Wt + O_W2;
    bf16* cWqk = Wt + O_QK;
    bf16* cWv  = Wt + O_WV;
    bf16* cWo  = Wt + O_WO;
    bf16* cF1  = Wt + O_F1;
    bf16* cF2  = Wt + O_F2;

    cvt_weights<<<3328, 256, 0, stream>>>(W1, W2, Wq, Wk, Wv, Wo, Fw1, Fw2, Wt);

    for (int ci = 0; ci < nch; ++ci) {
        const size_t roff = (size_t)ci * Mc * DMODEL;

        cvt_x<<<(int)(SL / 4096), 256, 0, stream>>>(x, roff, Xc);

        gemm_bf16<true, false, 0, false, false><<<dim3(DFF / 128, Mc / 128), 256, 0, stream>>>(
            xb + roff, Xc, (const bf16*)W1, (const bf16*)W1, cW1, cW1,
            b1, nullptr, 0, Hid, 0, Mc, DFF, DMODEL);
        gemm_bf16<false, false, 1, false, false><<<dim3(DMODEL / 128, Mc / 128), 256, 0, stream>>>(
            Hid, Hid, (const bf16*)W2, (const bf16*)W2, cW2, cW2,
            b2, nullptr, 0, X, roff, Mc, DMODEL, DFF);

        for (int l = 0; l < 2; ++l) {
            const size_t wOff   = (size_t)l * DMODEL * DMODEL;       // 1M
            const size_t fOff   = (size_t)l * FHID * DMODEL;         // 256K
            const size_t vOff   = (size_t)l * DMODEL;
            const size_t f1bOff = (size_t)l * FHID;

            const bf16* wqL = (const bf16*)Wq + wOff;
            const bf16* wkL = (const bf16*)Wk + wOff;
            const bf16* wvL = (const bf16*)Wv + wOff;
            const bf16* woL = (const bf16*)Wo + wOff;
            const bf16* f1L = (const bf16*)Fw1 + fOff;
            const bf16* f2L = (const bf16*)Fw2 + fOff;
            const bf16* qkLo = cWqk + (size_t)l * 2097152;
            const bf16* qkHi = qkLo + 1048576;

            ln_wave<<<Mc / 4, 256, 0, stream>>>(X, roff, ln1_g, ln1_b, vOff, Hh);
            // fused Q|K GEMM: N=2048, weight/bias select at col 1024 (uniform)
            gemm_bf16<false, false, 0, false, true><<<dim3(2048 / 128, Mc / 128), 256, 0, stream>>>(
                Hh, Hh, wqL, wkL, qkLo, qkHi,
                bq, bk, vOff, QKb, 0, Mc, 2048, DMODEL);
            // V GEMM with transposed store -> Vtb = V^T [1024][Mc]
            gemm_bf16<false, false, 0, true, false><<<dim3(DMODEL / 128, Mc / 128), 256, 0, stream>>>(
                Hh, Hh, wvL, wvL, cWv + wOff, cWv + wOff,
                bv, nullptr, vOff, Vtb, 0, Mc, DMODEL, DMODEL);

            attn_mfma<<<dim3(TSEQ / 64, NHEAD, c), 256, 0, stream>>>(QKb, Vtb, Ob);

            gemm_bf16<false, true, 1, false, false><<<dim3(DMODEL / 128, Mc / 128), 256, 0, stream>>>(
                Ob, Ob, woL, woL, cWo + wOff, cWo + wOff,
                bo, nullptr, vOff, X, roff, Mc, DMODEL, DMODEL);

            ln_wave<<<Mc / 4, 256, 0, stream>>>(X, roff, ln2_g, ln2_b, vOff, Hh);
            gemm_bf16<true, false, 0, false, false><<<dim3(FHID / 128, Mc / 128), 256, 0, stream>>>(
                Hh, Hh, f1L, f1L, cF1 + fOff, cF1 + fOff,
                Fb1, nullptr, f1bOff, Ffh, 0, Mc, FHID, DMODEL);
            gemm_bf16<false, true, 1, false, false><<<dim3(DMODEL / 128, Mc / 128), 256, 0, stream>>>(
                Ffh, Ffh, f2L, f2L, cF2 + fOff, cF2 + fOff,
                Fb2, nullptr, vOff, X, roff, Mc, DMODEL, FHID);
        }
    }
}

// Round 4
// 902.001 us; speedup vs baseline: 1.8070x; 1.4767x over previous
//
#include <hip/hip_runtime.h>
#include <hip/hip_bf16.h>

// ---------------------------------------------------------------------------
// CorrectTransformerAdaptor — Round 8: fp32-input path made cheap.
//   Round-3 evidence: early-exit never fired; inputs are fp32 (flag=0).
//   - flagbf_block(): ONE agent-scope acquire per block (was per-thread,
//     851K same-address coherent loads serializing on one L2/LLC slice).
//     Used by gemm/ln/cvt. detect unchanged.
//   - cvt_weights/cvt_x rewritten unit-stride: per instruction a wave reads
//     1KB contiguous fp32 and writes 512B contiguous bf16 (was 64-B lane
//     stride = 64 cache lines per instruction).
//   - GEMM core / attn / ln math and sync structure untouched.
// ---------------------------------------------------------------------------

#define DMODEL 1024
#define DFF 2048
#define FHID 256
#define NHEAD 8
#define DKH 128
#define TSEQ 1024

typedef __hip_bfloat16 bf16;
typedef __attribute__((ext_vector_type(8))) short bf16x8;   // 8 bf16 = 4 VGPR
typedef __attribute__((ext_vector_type(4))) float f32x4;

#define MFMA16(a, b, c) __builtin_amdgcn_mfma_f32_16x16x32_bf16(a, b, c, 0, 0, 0)

__device__ int g_is_bf16;

__device__ __forceinline__ bool flagbf() {            // per-thread (tiny kernels)
    return __hip_atomic_load(&g_is_bf16, __ATOMIC_ACQUIRE,
                             __HIP_MEMORY_SCOPE_AGENT) != 0;
}
// one coherent load per block, broadcast via LDS (needs all threads at entry)
__device__ __forceinline__ bool flagbf_block() {
    __shared__ int fsh;
    if (threadIdx.x == 0)
        fsh = __hip_atomic_load(&g_is_bf16, __ATOMIC_ACQUIRE,
                                __HIP_MEMORY_SCOPE_AGENT);
    __syncthreads();
    return fsh != 0;
}
__device__ __forceinline__ float gload(const void* p, size_t i, bool bf) {
    return bf ? __bfloat162float(((const bf16*)p)[i]) : ((const float*)p)[i];
}
__device__ __forceinline__ void gstore(void* p, size_t i, bool bf, float v) {
    if (bf) ((bf16*)p)[i] = __float2bfloat16(v);
    else    ((float*)p)[i] = v;
}

// direct global->LDS, 16 bytes/lane. LDS base must be wave-uniform (m104);
// lane writes at base + lane*16. Global address is per-lane.
__device__ __forceinline__ void async16(const bf16* g, const bf16* l) {
    __builtin_amdgcn_global_load_lds(
        (const __attribute__((address_space(1))) void*)g,
        (__attribute__((address_space(3))) void*)l, 16, 0, 0);
}

// ---- dtype probe (64 lanes, ballot) ---------------------------------------
__global__ void detect_kernel(const void* __restrict__ probe) {
    const int lane = threadIdx.x & 63;
    const bf16* h = (const bf16*)probe;
    int ok = 1;
    #pragma unroll
    for (int j = 0; j < 4; ++j) {
        float v = __bfloat162float(h[lane * 4 + j]);
        if (!(fabsf(v) <= 1000.0f)) ok = 0;   // catches huge AND NaN
    }
    unsigned long long m = __ballot(ok);
    if (lane == 0)
        __hip_atomic_store(&g_is_bf16, m == ~0ull ? 1 : 0, __ATOMIC_RELEASE,
                           __HIP_MEMORY_SCOPE_AGENT);
}

// ---- weight arena offsets (bf16 elems) — fp32-input path only -------------
#define O_W1  0ull
#define O_W2  2097152ull
#define O_QK  4194304ull
#define O_WV  8388608ull
#define O_WO  10485760ull
#define O_F1  12582912ull
#define O_F2  13107200ull
#define ARENA_ELEMS 13631488ull

// one block = 16384 elems; per iteration a wave does unit-stride float4
// reads (1KB/instr) and unit-stride uint2 bf16 writes (512B/instr).
__global__ __launch_bounds__(256) void cvt_weights(
        const void* W1, const void* W2, const void* Wq, const void* Wk,
        const void* Wv, const void* Wo, const void* F1, const void* F2,
        bf16* __restrict__ arena) {
    if (flagbf_block()) return;   // bf16 inputs: GEMMs read them directly
    int b = blockIdx.x;
    const float* src; bf16* dst;
    if      (b < 128)  {           src = (const float*)W1 + (size_t)b * 16384;
                         dst = arena + O_W1 + (size_t)b * 16384; }
    else if (b < 256)  { b -= 128; src = (const float*)W2 + (size_t)b * 16384;
                         dst = arena + O_W2 + (size_t)b * 16384; }
    else if (b < 384)  { b -= 256; src = (const float*)Wq + (size_t)b * 16384;
                         dst = arena + O_QK + (size_t)(b >> 6) * 2097152
                                            + (size_t)(b & 63) * 16384; }
    else if (b < 512)  { b -= 384; src = (const float*)Wk + (size_t)b * 16384;
                         dst = arena + O_QK + (size_t)(b >> 6) * 2097152
                                            + 1048576 + (size_t)(b & 63) * 16384; }
    else if (b < 640)  { b -= 512; src = (const float*)Wv + (size_t)b * 16384;
                         dst = arena + O_WV + (size_t)b * 16384; }
    else if (b < 768)  { b -= 640; src = (const float*)Wo + (size_t)b * 16384;
                         dst = arena + O_WO + (size_t)b * 16384; }
    else if (b < 800)  { b -= 768; src = (const float*)F1 + (size_t)b * 16384;
                         dst = arena + O_F1 + (size_t)b * 16384; }
    else               { b -= 800; src = (const float*)F2 + (size_t)b * 16384;
                         dst = arena + O_F2 + (size_t)b * 16384; }
    const int tid = threadIdx.x;
    #pragma unroll
    for (int it = 0; it < 16; ++it) {
        const int e = it * 1024 + tid * 4;
        float4 f = *(const float4*)(src + e);
        bf16 t[4] = {__float2bfloat16(f.x), __float2bfloat16(f.y),
                     __float2bfloat16(f.z), __float2bfloat16(f.w)};
        *(uint2*)(dst + e) = *(const uint2*)t;
    }
}

__global__ __launch_bounds__(256) void cvt_x(
        const void* __restrict__ X, size_t x_off, bf16* __restrict__ dst) {
    if (flagbf_block()) return;   // bf16 x is consumed in place
    const float* src = (const float*)X + x_off + (size_t)blockIdx.x * 16384;
    bf16* d = dst + (size_t)blockIdx.x * 16384;
    const int tid = threadIdx.x;
    #pragma unroll
    for (int it = 0; it < 16; ++it) {
        const int e = it * 1024 + tid * 4;
        float4 f = *(const float4*)(src + e);
        bf16 t[4] = {__float2bfloat16(f.x), __float2bfloat16(f.y),
                     __float2bfloat16(f.z), __float2bfloat16(f.w)};
        *(uint2*)(d + e) = *(const uint2*)t;
    }
}

// ---------------- m97-structure GEMM: C[M,N] = op(A[M,K] @ W[N,K]^T + b) ---
// Operand pointers come in (bf16-direct, converted-arena) pairs, selected on
// the device dtype flag; all row offsets folded host-side.
// CMODE: 0 = bf16 scratch C, 1 = flag-dtype harness buffer.
// TRANSC: store C^T (bf16) at C[col*M + row] — used to produce V^T.
// BIAS2: two-way weight/bias select at col 1024 (merged QK GEMM, uniform).
template <bool RELU, bool ADD, int CMODE, bool TRANSC, bool BIAS2>
__global__ __launch_bounds__(256) void gemm_bf16(
        const bf16* Abf, const bf16* Acv,
        const bf16* Wlo_bf, const bf16* Whi_bf,
        const bf16* Wlo_cv, const bf16* Whi_cv,
        const void* __restrict__ bias, const void* __restrict__ bias2,
        size_t b_off,
        void* __restrict__ C, size_t c_off,
        int M, int N, int K) {
    const bool fl = flagbf_block();
    const bf16* A   = fl ? Abf : Acv;
    const bf16* Wlo = fl ? Wlo_bf : Wlo_cv;
    const bf16* Whi = fl ? Whi_bf : Whi_cv;

    __shared__ __align__(16) bf16 As[128 * 64];
    __shared__ __align__(16) bf16 Bs[128 * 64];

    const int bm = blockIdx.y * 128, bn = blockIdx.x * 128;
    const int tid = threadIdx.x;
    const int wave = tid >> 6, lane = tid & 63;
    const int quad = lane >> 4, l15 = lane & 15;
    const int wr = wave >> 1, wc = wave & 1;
    const int l8 = lane >> 3, l7 = lane & 7;
    const int swz = l7 ^ l8;          // row&7 == l8 for our staging rows

    const bf16* Wp;
    int bnr;
    if (BIAS2 && bn >= 1024) { Wp = Whi; bnr = bn - 1024; }
    else                     { Wp = Wlo; bnr = bn; }

    f32x4 acc[4][4];
    #pragma unroll
    for (int i = 0; i < 4; ++i)
        #pragma unroll
        for (int j = 0; j < 4; ++j) acc[i][j] = (f32x4){0.f, 0.f, 0.f, 0.f};

    // wave w stages rows [w*32, w*32+32) of both tiles; 4 issues of 8 rows.
    const bf16* ga0 = A  + (size_t)(bm  + wave * 32 + l8) * K + swz * 8;
    const bf16* gb0 = Wp + (size_t)(bnr + wave * 32 + l8) * K + swz * 8;
    bf16* la0 = &As[(wave * 32) * 64];
    bf16* lb0 = &Bs[(wave * 32) * 64];

    for (int k0 = 0; k0 < K; k0 += 64) {
        __syncthreads();                       // prev iter frag reads done
        #pragma unroll
        for (int i = 0; i < 4; ++i) {
            async16(ga0 + (size_t)(i * 8) * K + k0, la0 + i * 512);
            async16(gb0 + (size_t)(i * 8) * K + k0, lb0 + i * 512);
        }
        __syncthreads();                       // vmcnt drained by compiler

        #pragma unroll
        for (int ks = 0; ks < 2; ++ks) {
            bf16x8 af[4], bfr[4];
            #pragma unroll
            for (int mi = 0; mi < 4; ++mi) {
                const int row = wr * 64 + mi * 16 + l15;
                af[mi] = *(const bf16x8*)
                    &As[row * 64 + ((((ks << 2) | quad) ^ (row & 7)) << 3)];
            }
            #pragma unroll
            for (int ni = 0; ni < 4; ++ni) {
                const int row = wc * 64 + ni * 16 + l15;
                bfr[ni] = *(const bf16x8*)
                    &Bs[row * 64 + ((((ks << 2) | quad) ^ (row & 7)) << 3)];
            }
            #pragma unroll
            for (int mi = 0; mi < 4; ++mi)
                #pragma unroll
                for (int ni = 0; ni < 4; ++ni)
                    acc[mi][ni] = MFMA16(af[mi], bfr[ni], acc[mi][ni]);
        }
    }

    // epilogue: acc row = quad*4+rr, col = lane&15 (verified m89/m91 layout)
    const bool cbf = CMODE ? fl : true;
    #pragma unroll
    for (int ni = 0; ni < 4; ++ni) {
        const int col = bn + wc * 64 + ni * 16 + l15;
        float bv;
        if (BIAS2) bv = col < 1024 ? gload(bias, b_off + col, fl)
                                   : gload(bias2, b_off + col - 1024, fl);
        else       bv = gload(bias, b_off + col, fl);
        #pragma unroll
        for (int mi = 0; mi < 4; ++mi) {
            const int row0 = bm + wr * 64 + mi * 16 + quad * 4;
            if (TRANSC) {
                bf16 pk[4];
                #pragma unroll
                for (int rr = 0; rr < 4; ++rr)
                    pk[rr] = __float2bfloat16(acc[mi][ni][rr] + bv);
                *(uint2*)((bf16*)C + c_off + (size_t)col * M + row0) =
                    *(const uint2*)pk;
            } else {
                #pragma unroll
                for (int rr = 0; rr < 4; ++rr) {
                    float v = acc[mi][ni][rr] + bv;
                    if (RELU) v = fmaxf(v, 0.f);
                    size_t idx = c_off + (size_t)(row0 + rr) * N + col;
                    if (ADD) v += gload(C, idx, cbf);
                    gstore(C, idx, cbf, v);
                }
            }
        }
    }
}

// ---------------- LayerNorm: one wave per row, shuffle-only ----------------
__global__ __launch_bounds__(256) void ln_wave(
        const void* __restrict__ X, size_t x_off,
        const void* __restrict__ g, const void* __restrict__ b, size_t gb_off,
        bf16* __restrict__ H) {
    const bool fl = flagbf_block();
    const int lane = threadIdx.x & 63;
    const int row = blockIdx.x * 4 + (threadIdx.x >> 6);
    const size_t xrow = x_off + (size_t)row * DMODEL;

    float v[16];
    if (fl) {
        const bf16* xp = (const bf16*)X + xrow;
        #pragma unroll
        for (int c = 0; c < 2; ++c) {
            uint4 raw = *(const uint4*)(xp + c * 512 + lane * 8);
            const bf16* rb = (const bf16*)&raw;
            #pragma unroll
            for (int j = 0; j < 8; ++j) v[c * 8 + j] = __bfloat162float(rb[j]);
        }
    } else {
        const float* xp = (const float*)X + xrow;
        #pragma unroll
        for (int c = 0; c < 4; ++c) {
            float4 f = *(const float4*)(xp + c * 256 + lane * 4);
            v[c * 4 + 0] = f.x; v[c * 4 + 1] = f.y;
            v[c * 4 + 2] = f.z; v[c * 4 + 3] = f.w;
        }
    }

    float s = 0.f;
    #pragma unroll
    for (int j = 0; j < 16; ++j) s += v[j];
    #pragma unroll
    for (int off = 32; off > 0; off >>= 1) s += __shfl_xor(s, off);
    const float mean = s * (1.f / DMODEL);

    float vs = 0.f;
    #pragma unroll
    for (int j = 0; j < 16; ++j) { float d = v[j] - mean; vs += d * d; }
    #pragma unroll
    for (int off = 32; off > 0; off >>= 1) vs += __shfl_xor(vs, off);
    const float rstd = rsqrtf(vs * (1.f / DMODEL) + 1e-12f);

    bf16* h = H + (size_t)row * DMODEL;
    if (fl) {
        const bf16* gp = (const bf16*)g + gb_off;
        const bf16* bp = (const bf16*)b + gb_off;
        #pragma unroll
        for (int c = 0; c < 2; ++c) {
            const int o = c * 512 + lane * 8;
            uint4 gr = *(const uint4*)(gp + o);
            uint4 br = *(const uint4*)(bp + o);
            const bf16* gg = (const bf16*)&gr;
            const bf16* bb = (const bf16*)&br;
            bf16 outv[8];
            #pragma unroll
            for (int j = 0; j < 8; ++j)
                outv[j] = __float2bfloat16((v[c * 8 + j] - mean) * rstd *
                          __bfloat162float(gg[j]) + __bfloat162float(bb[j]));
            *(uint4*)(h + o) = *(const uint4*)outv;
        }
    } else {
        const float* gp = (const float*)g + gb_off;
        const float* bp = (const float*)b + gb_off;
        #pragma unroll
        for (int c = 0; c < 4; ++c) {
            const int o = c * 256 + lane * 4;
            float4 gr = *(const float4*)(gp + o);
            float4 br = *(const float4*)(bp + o);
            const float gg[4] = {gr.x, gr.y, gr.z, gr.w};
            const float bb[4] = {br.x, br.y, br.z, br.w};
            bf16 outv[4];
            #pragma unroll
            for (int j = 0; j < 4; ++j)
                outv[j] = __float2bfloat16((v[c * 4 + j] - mean) * rstd * gg[j] + bb[j]);
            *(uint2*)(h + o) = *(const uint2*)outv;
        }
    }
}

// ---------------- Flash-style MFMA attention -------------------------------
// Grid: (TSEQ/64, NHEAD, c). Block: 256 threads = 4 waves, wave w owns
// q-rows [qt*64 + w*16, +16). K loop over 64-key tiles staged in LDS.
// QK: fused [Mc][2048] buffer (Q at col h*128, K at col 1024+h*128).
// Vg: V^T [1024][Mc] — staging is vectorized row loads (no transpose).
__global__ __launch_bounds__(256) void attn_mfma(
        const bf16* __restrict__ QK, const bf16* __restrict__ Vg,
        bf16* __restrict__ Om) {
    const int qt = blockIdx.x, h = blockIdx.y, bb = blockIdx.z;
    const int Mc = (int)gridDim.z * TSEQ;
    const int tid = threadIdx.x;
    const int wave = tid >> 6, lane = tid & 63;
    const int quad = lane >> 4, l15 = lane & 15;

    __shared__ __align__(16) bf16 Kt[64][128];
    __shared__ __align__(16) bf16 Vt[128][64];
    __shared__ __align__(16) bf16 Ps[4][16][72];

    const int qrow = qt * 64 + wave * 16 + l15;
    const float scale = 0.08838834764831845f;  // 1/sqrt(128)

    bf16x8 qf[4];
    #pragma unroll
    for (int kc = 0; kc < 4; ++kc) {
        uint4 raw = *(const uint4*)(QK + (size_t)(bb * TSEQ + qrow) * 2048 +
                                    h * DKH + kc * 32 + quad * 8);
        const bf16* rb = (const bf16*)&raw;
        bf16 tmp[8];
        #pragma unroll
        for (int j = 0; j < 8; ++j)
            tmp[j] = __float2bfloat16(__bfloat162float(rb[j]) * scale);
        qf[kc] = *(const bf16x8*)tmp;
    }

    f32x4 o[8];
    #pragma unroll
    for (int i = 0; i < 8; ++i) o[i] = (f32x4){0.f, 0.f, 0.f, 0.f};
    float m_i[4] = {-1e30f, -1e30f, -1e30f, -1e30f};
    float l_i[4] = {0.f, 0.f, 0.f, 0.f};

    const int skey = tid >> 2;              // K staging: row = key
    const int dseg = (tid & 3) * 32;
    const int sk7 = skey & 7;
    const int vd = tid >> 1;                // V staging: row = d
    const int vseg = (tid & 1) * 32;

    for (int kt = 0; kt < TSEQ / 64; ++kt) {
        __syncthreads();
        {
            const bf16* kp = QK + (size_t)(bb * TSEQ + kt * 64 + skey) * 2048 +
                             1024 + h * DKH + dseg;
            const bf16* vp = Vg + (size_t)(h * DKH + vd) * Mc + bb * TSEQ +
                             kt * 64 + vseg;
            uint4 kv[4], vv[4];
            #pragma unroll
            for (int g = 0; g < 4; ++g) { kv[g] = ((const uint4*)kp)[g]; vv[g] = ((const uint4*)vp)[g]; }
            #pragma unroll
            for (int g = 0; g < 4; ++g) {
                int d3 = (dseg >> 3) + g;
                *(uint4*)&Kt[skey][(d3 ^ sk7) << 3] = kv[g];
            }
            #pragma unroll
            for (int g = 0; g < 4; ++g) {
                int c = (vseg >> 3) + g;
                *(uint4*)&Vt[vd][(c ^ (vd & 7)) << 3] = vv[g];
            }
        }
        __syncthreads();

        f32x4 s[4];
        #pragma unroll
        for (int ni = 0; ni < 4; ++ni) s[ni] = (f32x4){0.f, 0.f, 0.f, 0.f};
        #pragma unroll
        for (int ni = 0; ni < 4; ++ni) {
            const int key = ni * 16 + l15;
            #pragma unroll
            for (int kc = 0; kc < 4; ++kc) {
                const int d3 = kc * 4 + quad;
                bf16x8 kb = *(const bf16x8*)&Kt[key][(d3 ^ (key & 7)) << 3];
                s[ni] = MFMA16(qf[kc], kb, s[ni]);
            }
        }

        float tm[4], al[4], ts[4];
        #pragma unroll
        for (int rr = 0; rr < 4; ++rr) {
            float v = fmaxf(fmaxf(s[0][rr], s[1][rr]), fmaxf(s[2][rr], s[3][rr]));
            v = fmaxf(v, __shfl_xor(v, 1));
            v = fmaxf(v, __shfl_xor(v, 2));
            v = fmaxf(v, __shfl_xor(v, 4));
            v = fmaxf(v, __shfl_xor(v, 8));
            tm[rr] = v;
        }
        #pragma unroll
        for (int rr = 0; rr < 4; ++rr) {
            float mn = fmaxf(m_i[rr], tm[rr]);
            al[rr] = __expf(m_i[rr] - mn);
            m_i[rr] = mn;
            ts[rr] = 0.f;
        }
        #pragma unroll
        for (int ni = 0; ni < 4; ++ni)
            #pragma unroll
            for (int rr = 0; rr < 4; ++rr) {
                float p = __expf(s[ni][rr] - m_i[rr]);
                s[ni][rr] = p;
                ts[rr] += p;
            }
        #pragma unroll
        for (int rr = 0; rr < 4; ++rr) {
            float v = ts[rr];
            v += __shfl_xor(v, 1);
            v += __shfl_xor(v, 2);
            v += __shfl_xor(v, 4);
            v += __shfl_xor(v, 8);
            l_i[rr] = l_i[rr] * al[rr] + v;
        }
        #pragma unroll
        for (int i = 0; i < 8; ++i)
            #pragma unroll
            for (int rr = 0; rr < 4; ++rr) o[i][rr] *= al[rr];

        #pragma unroll
        for (int ni = 0; ni < 4; ++ni)
            #pragma unroll
            for (int rr = 0; rr < 4; ++rr)
                Ps[wave][quad * 4 + rr][ni * 16 + l15] = __float2bfloat16(s[ni][rr]);
        __asm__ __volatile__("s_waitcnt lgkmcnt(0)" ::: "memory");
        bf16x8 pa[2];
        #pragma unroll
        for (int kc2 = 0; kc2 < 2; ++kc2)
            pa[kc2] = *(const bf16x8*)&Ps[wave][l15][kc2 * 32 + quad * 8];

        #pragma unroll
        for (int ni2 = 0; ni2 < 8; ++ni2) {
            const int d = ni2 * 16 + l15;
            #pragma unroll
            for (int kc2 = 0; kc2 < 2; ++kc2) {
                const int key3 = kc2 * 4 + quad;
                bf16x8 vb = *(const bf16x8*)&Vt[d][(key3 ^ (d & 7)) << 3];
                o[ni2] = MFMA16(pa[kc2], vb, o[ni2]);
            }
        }
    }

    const size_t obase = (size_t)bb * TSEQ * DMODEL + (size_t)h * DKH;
    #pragma unroll
    for (int ni2 = 0; ni2 < 8; ++ni2)
        #pragma unroll
        for (int rr = 0; rr < 4; ++rr) {
            int qr = qt * 64 + wave * 16 + quad * 4 + rr;
            Om[obase + (size_t)qr * DMODEL + ni2 * 16 + l15] =
                __float2bfloat16(o[ni2][rr] / l_i[rr]);
        }
}

// ---------------------------------------------------------------------------
extern "C" void kernel_launch(void* const* d_in, const int* in_sizes, int n_in,
                              void* d_out, int out_size, void* d_ws, size_t ws_size,
                              hipStream_t stream) {
    const void* x     = d_in[0];
    const void* W1    = d_in[1];
    const void* b1    = d_in[2];
    const void* W2    = d_in[3];
    const void* b2    = d_in[4];
    const void* ln1_g = d_in[5];
    const void* ln1_b = d_in[6];
    const void* ln2_g = d_in[7];
    const void* ln2_b = d_in[8];
    const void* Wq    = d_in[9];
    const void* bq    = d_in[10];
    const void* Wk    = d_in[11];
    const void* bk    = d_in[12];
    const void* Wv    = d_in[13];
    const void* bv    = d_in[14];
    const void* Wo    = d_in[15];
    const void* bo    = d_in[16];
    const void* Fw1   = d_in[17];
    const void* Fb1   = d_in[18];
    const void* Fw2   = d_in[19];
    const void* Fb2   = d_in[20];

    detect_kernel<<<1, 64, 0, stream>>>(W1);

    // workspace: [Hh | QKb | Vtb | Xc | weight arena], all bf16
    int c = 8;
    while (c > 1 &&
           (5ull * (size_t)c * (1ull << 20) + ARENA_ELEMS) * 2ull > ws_size)
        c >>= 1;
    const int nch = 8 / c;
    const int Mc = c * TSEQ;
    const size_t SL = (size_t)Mc * DMODEL;

    bf16* Hh  = (bf16*)d_ws;      // Mc x 1024
    bf16* QKb = Hh + SL;          // Mc x 2048 (fused Q|K)
    bf16* Vtb = QKb + 2 * SL;     // 1024 x Mc (V^T)
    bf16* Xc  = Vtb + SL;         // Mc x 1024 (fp32-input path only)
    bf16* Wt  = Xc + SL;          // weight arena (fp32-input path only)
    bf16* Hid = QKb;              // Mc x 2048 scratch (downsample hidden)
    bf16* Ffh = QKb;              // Mc x 256 scratch (FFN hidden)
    bf16* Ob  = Hh;               // attn output reuses LN buffer
    void* X = d_out;              // residual stream (flag dtype)

    const bf16* xb  = (const bf16*)x;
    bf16* cW1  = Wt + O_W1;
    bf16* cW2  = Wt + O_W2;
    bf16* cWqk = Wt + O_QK;
    bf16* cWv  = Wt + O_WV;
    bf16* cWo  = Wt + O_WO;
    bf16* cF1  = Wt + O_F1;
    bf16* cF2  = Wt + O_F2;

    cvt_weights<<<832, 256, 0, stream>>>(W1, W2, Wq, Wk, Wv, Wo, Fw1, Fw2, Wt);

    for (int ci = 0; ci < nch; ++ci) {
        const size_t roff = (size_t)ci * Mc * DMODEL;

        cvt_x<<<(int)(SL / 16384), 256, 0, stream>>>(x, roff, Xc);

        gemm_bf16<true, false, 0, false, false><<<dim3(DFF / 128, Mc / 128), 256, 0, stream>>>(
            xb + roff, Xc, (const bf16*)W1, (const bf16*)W1, cW1, cW1,
            b1, nullptr, 0, Hid, 0, Mc, DFF, DMODEL);
        gemm_bf16<false, false, 1, false, false><<<dim3(DMODEL / 128, Mc / 128), 256, 0, stream>>>(
            Hid, Hid, (const bf16*)W2, (const bf16*)W2, cW2, cW2,
            b2, nullptr, 0, X, roff, Mc, DMODEL, DFF);

        for (int l = 0; l < 2; ++l) {
            const size_t wOff   = (size_t)l * DMODEL * DMODEL;       // 1M
            const size_t fOff   = (size_t)l * FHID * DMODEL;         // 256K
            const size_t vOff   = (size_t)l * DMODEL;
            const size_t f1bOff = (size_t)l * FHID;

            const bf16* wqL = (const bf16*)Wq + wOff;
            const bf16* wkL = (const bf16*)Wk + wOff;
            const bf16* wvL = (const bf16*)Wv + wOff;
            const bf16* woL = (const bf16*)Wo + wOff;
            const bf16* f1L = (const bf16*)Fw1 + fOff;
            const bf16* f2L = (const bf16*)Fw2 + fOff;
            const bf16* qkLo = cWqk + (size_t)l * 2097152;
            const bf16* qkHi = qkLo + 1048576;

            ln_wave<<<Mc / 4, 256, 0, stream>>>(X, roff, ln1_g, ln1_b, vOff, Hh);
            // fused Q|K GEMM: N=2048, weight/bias select at col 1024 (uniform)
            gemm_bf16<false, false, 0, false, true><<<dim3(2048 / 128, Mc / 128), 256, 0, stream>>>(
                Hh, Hh, wqL, wkL, qkLo, qkHi,
                bq, bk, vOff, QKb, 0, Mc, 2048, DMODEL);
            // V GEMM with transposed store -> Vtb = V^T [1024][Mc]
            gemm_bf16<false, false, 0, true, false><<<dim3(DMODEL / 128, Mc / 128), 256, 0, stream>>>(
                Hh, Hh, wvL, wvL, cWv + wOff, cWv + wOff,
                bv, nullptr, vOff, Vtb, 0, Mc, DMODEL, DMODEL);

            attn_mfma<<<dim3(TSEQ / 64, NHEAD, c), 256, 0, stream>>>(QKb, Vtb, Ob);

            gemm_bf16<false, true, 1, false, false><<<dim3(DMODEL / 128, Mc / 128), 256, 0, stream>>>(
                Ob, Ob, woL, woL, cWo + wOff, cWo + wOff,
                bo, nullptr, vOff, X, roff, Mc, DMODEL, DMODEL);

            ln_wave<<<Mc / 4, 256, 0, stream>>>(X, roff, ln2_g, ln2_b, vOff, Hh);
            gemm_bf16<true, false, 0, false, false><<<dim3(FHID / 128, Mc / 128), 256, 0, stream>>>(
                Hh, Hh, f1L, f1L, cF1 + fOff, cF1 + fOff,
                Fb1, nullptr, f1bOff, Ffh, 0, Mc, FHID, DMODEL);
            gemm_bf16<false, true, 1, false, false><<<dim3(DMODEL / 128, Mc / 128), 256, 0, stream>>>(
                Ffh, Ffh, f2L, f2L, cF2 + fOff, cF2 + fOff,
                Fb2, nullptr, vOff, X, roff, Mc, DMODEL, FHID);
        }
    }
}

// Round 5
// 871.320 us; speedup vs baseline: 1.8706x; 1.0352x over previous
//
#include <hip/hip_runtime.h>
#include <hip/hip_bf16.h>

// ---------------------------------------------------------------------------
// CorrectTransformerAdaptor — Round 9: attn occupancy + defer-rescale.
//   Round-4 counters: attn 104 µs, Occupancy 25% (2 blocks/CU), VALU 36%,
//   Mfma 13.6% -> latency-bound with per-tile softmax overhead.
//   - attn QBLK 64->128: 8 waves/block (512 thr), same per-wave compute.
//     LDS 50KB -> 3 blocks/CU = 24 waves/CU (75% occupancy, was 25%).
//     Staging redone for 512 thr (2 x uint4/thread, same XOR swizzle pair).
//   - T13 defer-rescale: skip o-rescale + alpha exps when the running max
//     doesn't grow by >8 (wave-uniform __any gate). Exact up to bf16
//     scale-invariant rounding; P bounded by e^8.
//   - epilogue: 4 reciprocals instead of 32 divides.
//   - GEMM / LN / cvt unchanged from round 8 (passing, 902 µs).
// ---------------------------------------------------------------------------

#define DMODEL 1024
#define DFF 2048
#define FHID 256
#define NHEAD 8
#define DKH 128
#define TSEQ 1024

typedef __hip_bfloat16 bf16;
typedef __attribute__((ext_vector_type(8))) short bf16x8;   // 8 bf16 = 4 VGPR
typedef __attribute__((ext_vector_type(4))) float f32x4;

#define MFMA16(a, b, c) __builtin_amdgcn_mfma_f32_16x16x32_bf16(a, b, c, 0, 0, 0)

__device__ int g_is_bf16;

__device__ __forceinline__ bool flagbf() {            // per-thread (tiny kernels)
    return __hip_atomic_load(&g_is_bf16, __ATOMIC_ACQUIRE,
                             __HIP_MEMORY_SCOPE_AGENT) != 0;
}
// one coherent load per block, broadcast via LDS (needs all threads at entry)
__device__ __forceinline__ bool flagbf_block() {
    __shared__ int fsh;
    if (threadIdx.x == 0)
        fsh = __hip_atomic_load(&g_is_bf16, __ATOMIC_ACQUIRE,
                                __HIP_MEMORY_SCOPE_AGENT);
    __syncthreads();
    return fsh != 0;
}
__device__ __forceinline__ float gload(const void* p, size_t i, bool bf) {
    return bf ? __bfloat162float(((const bf16*)p)[i]) : ((const float*)p)[i];
}
__device__ __forceinline__ void gstore(void* p, size_t i, bool bf, float v) {
    if (bf) ((bf16*)p)[i] = __float2bfloat16(v);
    else    ((float*)p)[i] = v;
}

// direct global->LDS, 16 bytes/lane. LDS base must be wave-uniform (m104);
// lane writes at base + lane*16. Global address is per-lane.
__device__ __forceinline__ void async16(const bf16* g, const bf16* l) {
    __builtin_amdgcn_global_load_lds(
        (const __attribute__((address_space(1))) void*)g,
        (__attribute__((address_space(3))) void*)l, 16, 0, 0);
}

// ---- dtype probe (64 lanes, ballot) ---------------------------------------
__global__ void detect_kernel(const void* __restrict__ probe) {
    const int lane = threadIdx.x & 63;
    const bf16* h = (const bf16*)probe;
    int ok = 1;
    #pragma unroll
    for (int j = 0; j < 4; ++j) {
        float v = __bfloat162float(h[lane * 4 + j]);
        if (!(fabsf(v) <= 1000.0f)) ok = 0;   // catches huge AND NaN
    }
    unsigned long long m = __ballot(ok);
    if (lane == 0)
        __hip_atomic_store(&g_is_bf16, m == ~0ull ? 1 : 0, __ATOMIC_RELEASE,
                           __HIP_MEMORY_SCOPE_AGENT);
}

// ---- weight arena offsets (bf16 elems) — fp32-input path only -------------
#define O_W1  0ull
#define O_W2  2097152ull
#define O_QK  4194304ull
#define O_WV  8388608ull
#define O_WO  10485760ull
#define O_F1  12582912ull
#define O_F2  13107200ull
#define ARENA_ELEMS 13631488ull

// one block = 16384 elems; per iteration a wave does unit-stride float4
// reads (1KB/instr) and unit-stride uint2 bf16 writes (512B/instr).
__global__ __launch_bounds__(256) void cvt_weights(
        const void* W1, const void* W2, const void* Wq, const void* Wk,
        const void* Wv, const void* Wo, const void* F1, const void* F2,
        bf16* __restrict__ arena) {
    if (flagbf_block()) return;   // bf16 inputs: GEMMs read them directly
    int b = blockIdx.x;
    const float* src; bf16* dst;
    if      (b < 128)  {           src = (const float*)W1 + (size_t)b * 16384;
                         dst = arena + O_W1 + (size_t)b * 16384; }
    else if (b < 256)  { b -= 128; src = (const float*)W2 + (size_t)b * 16384;
                         dst = arena + O_W2 + (size_t)b * 16384; }
    else if (b < 384)  { b -= 256; src = (const float*)Wq + (size_t)b * 16384;
                         dst = arena + O_QK + (size_t)(b >> 6) * 2097152
                                            + (size_t)(b & 63) * 16384; }
    else if (b < 512)  { b -= 384; src = (const float*)Wk + (size_t)b * 16384;
                         dst = arena + O_QK + (size_t)(b >> 6) * 2097152
                                            + 1048576 + (size_t)(b & 63) * 16384; }
    else if (b < 640)  { b -= 512; src = (const float*)Wv + (size_t)b * 16384;
                         dst = arena + O_WV + (size_t)b * 16384; }
    else if (b < 768)  { b -= 640; src = (const float*)Wo + (size_t)b * 16384;
                         dst = arena + O_WO + (size_t)b * 16384; }
    else if (b < 800)  { b -= 768; src = (const float*)F1 + (size_t)b * 16384;
                         dst = arena + O_F1 + (size_t)b * 16384; }
    else               { b -= 800; src = (const float*)F2 + (size_t)b * 16384;
                         dst = arena + O_F2 + (size_t)b * 16384; }
    const int tid = threadIdx.x;
    #pragma unroll
    for (int it = 0; it < 16; ++it) {
        const int e = it * 1024 + tid * 4;
        float4 f = *(const float4*)(src + e);
        bf16 t[4] = {__float2bfloat16(f.x), __float2bfloat16(f.y),
                     __float2bfloat16(f.z), __float2bfloat16(f.w)};
        *(uint2*)(dst + e) = *(const uint2*)t;
    }
}

__global__ __launch_bounds__(256) void cvt_x(
        const void* __restrict__ X, size_t x_off, bf16* __restrict__ dst) {
    if (flagbf_block()) return;   // bf16 x is consumed in place
    const float* src = (const float*)X + x_off + (size_t)blockIdx.x * 16384;
    bf16* d = dst + (size_t)blockIdx.x * 16384;
    const int tid = threadIdx.x;
    #pragma unroll
    for (int it = 0; it < 16; ++it) {
        const int e = it * 1024 + tid * 4;
        float4 f = *(const float4*)(src + e);
        bf16 t[4] = {__float2bfloat16(f.x), __float2bfloat16(f.y),
                     __float2bfloat16(f.z), __float2bfloat16(f.w)};
        *(uint2*)(d + e) = *(const uint2*)t;
    }
}

// ---------------- m97-structure GEMM: C[M,N] = op(A[M,K] @ W[N,K]^T + b) ---
// Operand pointers come in (bf16-direct, converted-arena) pairs, selected on
// the device dtype flag; all row offsets folded host-side.
// CMODE: 0 = bf16 scratch C, 1 = flag-dtype harness buffer.
// TRANSC: store C^T (bf16) at C[col*M + row] — used to produce V^T.
// BIAS2: two-way weight/bias select at col 1024 (merged QK GEMM, uniform).
template <bool RELU, bool ADD, int CMODE, bool TRANSC, bool BIAS2>
__global__ __launch_bounds__(256) void gemm_bf16(
        const bf16* Abf, const bf16* Acv,
        const bf16* Wlo_bf, const bf16* Whi_bf,
        const bf16* Wlo_cv, const bf16* Whi_cv,
        const void* __restrict__ bias, const void* __restrict__ bias2,
        size_t b_off,
        void* __restrict__ C, size_t c_off,
        int M, int N, int K) {
    const bool fl = flagbf_block();
    const bf16* A   = fl ? Abf : Acv;
    const bf16* Wlo = fl ? Wlo_bf : Wlo_cv;
    const bf16* Whi = fl ? Whi_bf : Whi_cv;

    __shared__ __align__(16) bf16 As[128 * 64];
    __shared__ __align__(16) bf16 Bs[128 * 64];

    const int bm = blockIdx.y * 128, bn = blockIdx.x * 128;
    const int tid = threadIdx.x;
    const int wave = tid >> 6, lane = tid & 63;
    const int quad = lane >> 4, l15 = lane & 15;
    const int wr = wave >> 1, wc = wave & 1;
    const int l8 = lane >> 3, l7 = lane & 7;
    const int swz = l7 ^ l8;          // row&7 == l8 for our staging rows

    const bf16* Wp;
    int bnr;
    if (BIAS2 && bn >= 1024) { Wp = Whi; bnr = bn - 1024; }
    else                     { Wp = Wlo; bnr = bn; }

    f32x4 acc[4][4];
    #pragma unroll
    for (int i = 0; i < 4; ++i)
        #pragma unroll
        for (int j = 0; j < 4; ++j) acc[i][j] = (f32x4){0.f, 0.f, 0.f, 0.f};

    // wave w stages rows [w*32, w*32+32) of both tiles; 4 issues of 8 rows.
    const bf16* ga0 = A  + (size_t)(bm  + wave * 32 + l8) * K + swz * 8;
    const bf16* gb0 = Wp + (size_t)(bnr + wave * 32 + l8) * K + swz * 8;
    bf16* la0 = &As[(wave * 32) * 64];
    bf16* lb0 = &Bs[(wave * 32) * 64];

    for (int k0 = 0; k0 < K; k0 += 64) {
        __syncthreads();                       // prev iter frag reads done
        #pragma unroll
        for (int i = 0; i < 4; ++i) {
            async16(ga0 + (size_t)(i * 8) * K + k0, la0 + i * 512);
            async16(gb0 + (size_t)(i * 8) * K + k0, lb0 + i * 512);
        }
        __syncthreads();                       // vmcnt drained by compiler

        #pragma unroll
        for (int ks = 0; ks < 2; ++ks) {
            bf16x8 af[4], bfr[4];
            #pragma unroll
            for (int mi = 0; mi < 4; ++mi) {
                const int row = wr * 64 + mi * 16 + l15;
                af[mi] = *(const bf16x8*)
                    &As[row * 64 + ((((ks << 2) | quad) ^ (row & 7)) << 3)];
            }
            #pragma unroll
            for (int ni = 0; ni < 4; ++ni) {
                const int row = wc * 64 + ni * 16 + l15;
                bfr[ni] = *(const bf16x8*)
                    &Bs[row * 64 + ((((ks << 2) | quad) ^ (row & 7)) << 3)];
            }
            #pragma unroll
            for (int mi = 0; mi < 4; ++mi)
                #pragma unroll
                for (int ni = 0; ni < 4; ++ni)
                    acc[mi][ni] = MFMA16(af[mi], bfr[ni], acc[mi][ni]);
        }
    }

    // epilogue: acc row = quad*4+rr, col = lane&15 (verified m89/m91 layout)
    const bool cbf = CMODE ? fl : true;
    #pragma unroll
    for (int ni = 0; ni < 4; ++ni) {
        const int col = bn + wc * 64 + ni * 16 + l15;
        float bv;
        if (BIAS2) bv = col < 1024 ? gload(bias, b_off + col, fl)
                                   : gload(bias2, b_off + col - 1024, fl);
        else       bv = gload(bias, b_off + col, fl);
        #pragma unroll
        for (int mi = 0; mi < 4; ++mi) {
            const int row0 = bm + wr * 64 + mi * 16 + quad * 4;
            if (TRANSC) {
                bf16 pk[4];
                #pragma unroll
                for (int rr = 0; rr < 4; ++rr)
                    pk[rr] = __float2bfloat16(acc[mi][ni][rr] + bv);
                *(uint2*)((bf16*)C + c_off + (size_t)col * M + row0) =
                    *(const uint2*)pk;
            } else {
                #pragma unroll
                for (int rr = 0; rr < 4; ++rr) {
                    float v = acc[mi][ni][rr] + bv;
                    if (RELU) v = fmaxf(v, 0.f);
                    size_t idx = c_off + (size_t)(row0 + rr) * N + col;
                    if (ADD) v += gload(C, idx, cbf);
                    gstore(C, idx, cbf, v);
                }
            }
        }
    }
}

// ---------------- LayerNorm: one wave per row, shuffle-only ----------------
__global__ __launch_bounds__(256) void ln_wave(
        const void* __restrict__ X, size_t x_off,
        const void* __restrict__ g, const void* __restrict__ b, size_t gb_off,
        bf16* __restrict__ H) {
    const bool fl = flagbf_block();
    const int lane = threadIdx.x & 63;
    const int row = blockIdx.x * 4 + (threadIdx.x >> 6);
    const size_t xrow = x_off + (size_t)row * DMODEL;

    float v[16];
    if (fl) {
        const bf16* xp = (const bf16*)X + xrow;
        #pragma unroll
        for (int c = 0; c < 2; ++c) {
            uint4 raw = *(const uint4*)(xp + c * 512 + lane * 8);
            const bf16* rb = (const bf16*)&raw;
            #pragma unroll
            for (int j = 0; j < 8; ++j) v[c * 8 + j] = __bfloat162float(rb[j]);
        }
    } else {
        const float* xp = (const float*)X + xrow;
        #pragma unroll
        for (int c = 0; c < 4; ++c) {
            float4 f = *(const float4*)(xp + c * 256 + lane * 4);
            v[c * 4 + 0] = f.x; v[c * 4 + 1] = f.y;
            v[c * 4 + 2] = f.z; v[c * 4 + 3] = f.w;
        }
    }

    float s = 0.f;
    #pragma unroll
    for (int j = 0; j < 16; ++j) s += v[j];
    #pragma unroll
    for (int off = 32; off > 0; off >>= 1) s += __shfl_xor(s, off);
    const float mean = s * (1.f / DMODEL);

    float vs = 0.f;
    #pragma unroll
    for (int j = 0; j < 16; ++j) { float d = v[j] - mean; vs += d * d; }
    #pragma unroll
    for (int off = 32; off > 0; off >>= 1) vs += __shfl_xor(vs, off);
    const float rstd = rsqrtf(vs * (1.f / DMODEL) + 1e-12f);

    bf16* h = H + (size_t)row * DMODEL;
    if (fl) {
        const bf16* gp = (const bf16*)g + gb_off;
        const bf16* bp = (const bf16*)b + gb_off;
        #pragma unroll
        for (int c = 0; c < 2; ++c) {
            const int o = c * 512 + lane * 8;
            uint4 gr = *(const uint4*)(gp + o);
            uint4 br = *(const uint4*)(bp + o);
            const bf16* gg = (const bf16*)&gr;
            const bf16* bb = (const bf16*)&br;
            bf16 outv[8];
            #pragma unroll
            for (int j = 0; j < 8; ++j)
                outv[j] = __float2bfloat16((v[c * 8 + j] - mean) * rstd *
                          __bfloat162float(gg[j]) + __bfloat162float(bb[j]));
            *(uint4*)(h + o) = *(const uint4*)outv;
        }
    } else {
        const float* gp = (const float*)g + gb_off;
        const float* bp = (const float*)b + gb_off;
        #pragma unroll
        for (int c = 0; c < 4; ++c) {
            const int o = c * 256 + lane * 4;
            float4 gr = *(const float4*)(gp + o);
            float4 br = *(const float4*)(bp + o);
            const float gg[4] = {gr.x, gr.y, gr.z, gr.w};
            const float bb[4] = {br.x, br.y, br.z, br.w};
            bf16 outv[4];
            #pragma unroll
            for (int j = 0; j < 4; ++j)
                outv[j] = __float2bfloat16((v[c * 4 + j] - mean) * rstd * gg[j] + bb[j]);
            *(uint2*)(h + o) = *(const uint2*)outv;
        }
    }
}

// ---------------- Flash-style MFMA attention -------------------------------
// Grid: (TSEQ/128, NHEAD, c). Block: 512 threads = 8 waves, wave w owns
// q-rows [qt*128 + w*16, +16). K loop over 64-key tiles staged in LDS.
// QK: fused [Mc][2048] buffer (Q at col h*128, K at col 1024+h*128).
// Vg: V^T [1024][Mc] — staging is vectorized row loads (no transpose).
// LDS 50KB -> 3 blocks/CU (24 waves). T13 defer-rescale on the softmax.
__global__ __launch_bounds__(512) void attn_mfma(
        const bf16* __restrict__ QK, const bf16* __restrict__ Vg,
        bf16* __restrict__ Om) {
    const int qt = blockIdx.x, h = blockIdx.y, bb = blockIdx.z;
    const int Mc = (int)gridDim.z * TSEQ;
    const int tid = threadIdx.x;
    const int wave = tid >> 6, lane = tid & 63;
    const int quad = lane >> 4, l15 = lane & 15;

    __shared__ __align__(16) bf16 Kt[64][128];
    __shared__ __align__(16) bf16 Vt[128][64];
    __shared__ __align__(16) bf16 Ps[8][16][72];

    const int qrow = qt * 128 + wave * 16 + l15;
    const float scale = 0.08838834764831845f;  // 1/sqrt(128)

    bf16x8 qf[4];
    #pragma unroll
    for (int kc = 0; kc < 4; ++kc) {
        uint4 raw = *(const uint4*)(QK + (size_t)(bb * TSEQ + qrow) * 2048 +
                                    h * DKH + kc * 32 + quad * 8);
        const bf16* rb = (const bf16*)&raw;
        bf16 tmp[8];
        #pragma unroll
        for (int j = 0; j < 8; ++j)
            tmp[j] = __float2bfloat16(__bfloat162float(rb[j]) * scale);
        qf[kc] = *(const bf16x8*)tmp;
    }

    f32x4 o[8];
    #pragma unroll
    for (int i = 0; i < 8; ++i) o[i] = (f32x4){0.f, 0.f, 0.f, 0.f};
    float m_i[4] = {-1e30f, -1e30f, -1e30f, -1e30f};
    float l_i[4] = {0.f, 0.f, 0.f, 0.f};

    const int skey = tid >> 3;              // K staging: row = key (0..63)
    const int dseg = (tid & 7) * 16;        // 2 x uint4 per thread
    const int sk7 = skey & 7;
    const int vd = tid >> 2;                // V staging: row = d (0..127)
    const int vseg = (tid & 3) * 16;        // 2 x uint4 per thread

    for (int kt = 0; kt < TSEQ / 64; ++kt) {
        __syncthreads();
        {
            const bf16* kp = QK + (size_t)(bb * TSEQ + kt * 64 + skey) * 2048 +
                             1024 + h * DKH + dseg;
            const bf16* vp = Vg + (size_t)(h * DKH + vd) * Mc + bb * TSEQ +
                             kt * 64 + vseg;
            uint4 kv[2], vv[2];
            #pragma unroll
            for (int g = 0; g < 2; ++g) { kv[g] = ((const uint4*)kp)[g]; vv[g] = ((const uint4*)vp)[g]; }
            #pragma unroll
            for (int g = 0; g < 2; ++g) {
                int c = (dseg >> 3) + g;
                *(uint4*)&Kt[skey][(c ^ sk7) << 3] = kv[g];
            }
            #pragma unroll
            for (int g = 0; g < 2; ++g) {
                int c = (vseg >> 3) + g;
                *(uint4*)&Vt[vd][(c ^ (vd & 7)) << 3] = vv[g];
            }
        }
        __syncthreads();

        f32x4 s[4];
        #pragma unroll
        for (int ni = 0; ni < 4; ++ni) s[ni] = (f32x4){0.f, 0.f, 0.f, 0.f};
        #pragma unroll
        for (int ni = 0; ni < 4; ++ni) {
            const int key = ni * 16 + l15;
            #pragma unroll
            for (int kc = 0; kc < 4; ++kc) {
                const int d3 = kc * 4 + quad;
                bf16x8 kb = *(const bf16x8*)&Kt[key][(d3 ^ (key & 7)) << 3];
                s[ni] = MFMA16(qf[kc], kb, s[ni]);
            }
        }

        float tm[4], ts[4];
        #pragma unroll
        for (int rr = 0; rr < 4; ++rr) {
            float v = fmaxf(fmaxf(s[0][rr], s[1][rr]), fmaxf(s[2][rr], s[3][rr]));
            v = fmaxf(v, __shfl_xor(v, 1));
            v = fmaxf(v, __shfl_xor(v, 2));
            v = fmaxf(v, __shfl_xor(v, 4));
            v = fmaxf(v, __shfl_xor(v, 8));
            tm[rr] = v;
        }
        // T13: only rescale when the running max grows by > 8 (wave-uniform)
        int grow = 0;
        #pragma unroll
        for (int rr = 0; rr < 4; ++rr)
            grow |= (tm[rr] > m_i[rr] + 8.f) ? 1 : 0;
        if (__any(grow)) {
            float al[4];
            #pragma unroll
            for (int rr = 0; rr < 4; ++rr) {
                float mn = fmaxf(m_i[rr], tm[rr]);
                al[rr] = __expf(m_i[rr] - mn);
                m_i[rr] = mn;
                l_i[rr] *= al[rr];
            }
            #pragma unroll
            for (int i = 0; i < 8; ++i)
                #pragma unroll
                for (int rr = 0; rr < 4; ++rr) o[i][rr] *= al[rr];
        }
        #pragma unroll
        for (int rr = 0; rr < 4; ++rr) ts[rr] = 0.f;
        #pragma unroll
        for (int ni = 0; ni < 4; ++ni)
            #pragma unroll
            for (int rr = 0; rr < 4; ++rr) {
                float p = __expf(s[ni][rr] - m_i[rr]);
                s[ni][rr] = p;
                ts[rr] += p;
            }
        #pragma unroll
        for (int rr = 0; rr < 4; ++rr) {
            float v = ts[rr];
            v += __shfl_xor(v, 1);
            v += __shfl_xor(v, 2);
            v += __shfl_xor(v, 4);
            v += __shfl_xor(v, 8);
            l_i[rr] += v;
        }

        #pragma unroll
        for (int ni = 0; ni < 4; ++ni)
            #pragma unroll
            for (int rr = 0; rr < 4; ++rr)
                Ps[wave][quad * 4 + rr][ni * 16 + l15] = __float2bfloat16(s[ni][rr]);
        __asm__ __volatile__("s_waitcnt lgkmcnt(0)" ::: "memory");
        bf16x8 pa[2];
        #pragma unroll
        for (int kc2 = 0; kc2 < 2; ++kc2)
            pa[kc2] = *(const bf16x8*)&Ps[wave][l15][kc2 * 32 + quad * 8];

        #pragma unroll
        for (int ni2 = 0; ni2 < 8; ++ni2) {
            const int d = ni2 * 16 + l15;
            #pragma unroll
            for (int kc2 = 0; kc2 < 2; ++kc2) {
                const int key3 = kc2 * 4 + quad;
                bf16x8 vb = *(const bf16x8*)&Vt[d][(key3 ^ (d & 7)) << 3];
                o[ni2] = MFMA16(pa[kc2], vb, o[ni2]);
            }
        }
    }

    float rinv[4];
    #pragma unroll
    for (int rr = 0; rr < 4; ++rr) rinv[rr] = 1.0f / l_i[rr];
    const size_t obase = (size_t)bb * TSEQ * DMODEL + (size_t)h * DKH;
    #pragma unroll
    for (int ni2 = 0; ni2 < 8; ++ni2)
        #pragma unroll
        for (int rr = 0; rr < 4; ++rr) {
            int qr = qt * 128 + wave * 16 + quad * 4 + rr;
            Om[obase + (size_t)qr * DMODEL + ni2 * 16 + l15] =
                __float2bfloat16(o[ni2][rr] * rinv[rr]);
        }
}

// ---------------------------------------------------------------------------
extern "C" void kernel_launch(void* const* d_in, const int* in_sizes, int n_in,
                              void* d_out, int out_size, void* d_ws, size_t ws_size,
                              hipStream_t stream) {
    const void* x     = d_in[0];
    const void* W1    = d_in[1];
    const void* b1    = d_in[2];
    const void* W2    = d_in[3];
    const void* b2    = d_in[4];
    const void* ln1_g = d_in[5];
    const void* ln1_b = d_in[6];
    const void* ln2_g = d_in[7];
    const void* ln2_b = d_in[8];
    const void* Wq    = d_in[9];
    const void* bq    = d_in[10];
    const void* Wk    = d_in[11];
    const void* bk    = d_in[12];
    const void* Wv    = d_in[13];
    const void* bv    = d_in[14];
    const void* Wo    = d_in[15];
    const void* bo    = d_in[16];
    const void* Fw1   = d_in[17];
    const void* Fb1   = d_in[18];
    const void* Fw2   = d_in[19];
    const void* Fb2   = d_in[20];

    detect_kernel<<<1, 64, 0, stream>>>(W1);

    // workspace: [Hh | QKb | Vtb | Xc | weight arena], all bf16
    int c = 8;
    while (c > 1 &&
           (5ull * (size_t)c * (1ull << 20) + ARENA_ELEMS) * 2ull > ws_size)
        c >>= 1;
    const int nch = 8 / c;
    const int Mc = c * TSEQ;
    const size_t SL = (size_t)Mc * DMODEL;

    bf16* Hh  = (bf16*)d_ws;      // Mc x 1024
    bf16* QKb = Hh + SL;          // Mc x 2048 (fused Q|K)
    bf16* Vtb = QKb + 2 * SL;     // 1024 x Mc (V^T)
    bf16* Xc  = Vtb + SL;         // Mc x 1024 (fp32-input path only)
    bf16* Wt  = Xc + SL;          // weight arena (fp32-input path only)
    bf16* Hid = QKb;              // Mc x 2048 scratch (downsample hidden)
    bf16* Ffh = QKb;              // Mc x 256 scratch (FFN hidden)
    bf16* Ob  = Hh;               // attn output reuses LN buffer
    void* X = d_out;              // residual stream (flag dtype)

    const bf16* xb  = (const bf16*)x;
    bf16* cW1  = Wt + O_W1;
    bf16* cW2  = Wt + O_W2;
    bf16* cWqk = Wt + O_QK;
    bf16* cWv  = Wt + O_WV;
    bf16* cWo  = Wt + O_WO;
    bf16* cF1  = Wt + O_F1;
    bf16* cF2  = Wt + O_F2;

    cvt_weights<<<832, 256, 0, stream>>>(W1, W2, Wq, Wk, Wv, Wo, Fw1, Fw2, Wt);

    for (int ci = 0; ci < nch; ++ci) {
        const size_t roff = (size_t)ci * Mc * DMODEL;

        cvt_x<<<(int)(SL / 16384), 256, 0, stream>>>(x, roff, Xc);

        gemm_bf16<true, false, 0, false, false><<<dim3(DFF / 128, Mc / 128), 256, 0, stream>>>(
            xb + roff, Xc, (const bf16*)W1, (const bf16*)W1, cW1, cW1,
            b1, nullptr, 0, Hid, 0, Mc, DFF, DMODEL);
        gemm_bf16<false, false, 1, false, false><<<dim3(DMODEL / 128, Mc / 128), 256, 0, stream>>>(
            Hid, Hid, (const bf16*)W2, (const bf16*)W2, cW2, cW2,
            b2, nullptr, 0, X, roff, Mc, DMODEL, DFF);

        for (int l = 0; l < 2; ++l) {
            const size_t wOff   = (size_t)l * DMODEL * DMODEL;       // 1M
            const size_t fOff   = (size_t)l * FHID * DMODEL;         // 256K
            const size_t vOff   = (size_t)l * DMODEL;
            const size_t f1bOff = (size_t)l * FHID;

            const bf16* wqL = (const bf16*)Wq + wOff;
            const bf16* wkL = (const bf16*)Wk + wOff;
            const bf16* wvL = (const bf16*)Wv + wOff;
            const bf16* woL = (const bf16*)Wo + wOff;
            const bf16* f1L = (const bf16*)Fw1 + fOff;
            const bf16* f2L = (const bf16*)Fw2 + fOff;
            const bf16* qkLo = cWqk + (size_t)l * 2097152;
            const bf16* qkHi = qkLo + 1048576;

            ln_wave<<<Mc / 4, 256, 0, stream>>>(X, roff, ln1_g, ln1_b, vOff, Hh);
            // fused Q|K GEMM: N=2048, weight/bias select at col 1024 (uniform)
            gemm_bf16<false, false, 0, false, true><<<dim3(2048 / 128, Mc / 128), 256, 0, stream>>>(
                Hh, Hh, wqL, wkL, qkLo, qkHi,
                bq, bk, vOff, QKb, 0, Mc, 2048, DMODEL);
            // V GEMM with transposed store -> Vtb = V^T [1024][Mc]
            gemm_bf16<false, false, 0, true, false><<<dim3(DMODEL / 128, Mc / 128), 256, 0, stream>>>(
                Hh, Hh, wvL, wvL, cWv + wOff, cWv + wOff,
                bv, nullptr, vOff, Vtb, 0, Mc, DMODEL, DMODEL);

            attn_mfma<<<dim3(TSEQ / 128, NHEAD, c), 512, 0, stream>>>(QKb, Vtb, Ob);

            gemm_bf16<false, true, 1, false, false><<<dim3(DMODEL / 128, Mc / 128), 256, 0, stream>>>(
                Ob, Ob, woL, woL, cWo + wOff, cWo + wOff,
                bo, nullptr, vOff, X, roff, Mc, DMODEL, DMODEL);

            ln_wave<<<Mc / 4, 256, 0, stream>>>(X, roff, ln2_g, ln2_b, vOff, Hh);
            gemm_bf16<true, false, 0, false, false><<<dim3(FHID / 128, Mc / 128), 256, 0, stream>>>(
                Hh, Hh, f1L, f1L, cF1 + fOff, cF1 + fOff,
                Fb1, nullptr, f1bOff, Ffh, 0, Mc, FHID, DMODEL);
            gemm_bf16<false, true, 1, false, false><<<dim3(DMODEL / 128, Mc / 128), 256, 0, stream>>>(
                Ffh, Ffh, f2L, f2L, cF2 + fOff, cF2 + fOff,
                Fb2, nullptr, vOff, X, roff, Mc, DMODEL, FHID);
        }
    }
}

// Round 6
// 848.749 us; speedup vs baseline: 1.9204x; 1.0266x over previous
//
#include <hip/hip_runtime.h>
#include <hip/hip_bf16.h>

// ---------------------------------------------------------------------------
// CorrectTransformerAdaptor — Round 10: XCD-locality swizzles (T1).
//   Round-5 evidence: attn FETCH 139MB vs ~50MB ideal — qt-blocks sharing
//   K/V round-robin across XCDs, each private L2 refetches K/V from HBM.
//   - attn: bijective remap so each XCD owns whole (bb, all-head) groups
//     (heads share QK cache lines; per-XCD working set ~4MB = L2).
//   - gemm: bm-band remap — each XCD gets a contiguous band of bm rows
//     (A-panels fetched once per XCD, W streams resident).
//   Pure index remaps: no math / sync-structure changes vs round 9.
// ---------------------------------------------------------------------------

#define DMODEL 1024
#define DFF 2048
#define FHID 256
#define NHEAD 8
#define DKH 128
#define TSEQ 1024

typedef __hip_bfloat16 bf16;
typedef __attribute__((ext_vector_type(8))) short bf16x8;   // 8 bf16 = 4 VGPR
typedef __attribute__((ext_vector_type(4))) float f32x4;

#define MFMA16(a, b, c) __builtin_amdgcn_mfma_f32_16x16x32_bf16(a, b, c, 0, 0, 0)

__device__ int g_is_bf16;

__device__ __forceinline__ bool flagbf() {            // per-thread (tiny kernels)
    return __hip_atomic_load(&g_is_bf16, __ATOMIC_ACQUIRE,
                             __HIP_MEMORY_SCOPE_AGENT) != 0;
}
// one coherent load per block, broadcast via LDS (needs all threads at entry)
__device__ __forceinline__ bool flagbf_block() {
    __shared__ int fsh;
    if (threadIdx.x == 0)
        fsh = __hip_atomic_load(&g_is_bf16, __ATOMIC_ACQUIRE,
                                __HIP_MEMORY_SCOPE_AGENT);
    __syncthreads();
    return fsh != 0;
}
__device__ __forceinline__ float gload(const void* p, size_t i, bool bf) {
    return bf ? __bfloat162float(((const bf16*)p)[i]) : ((const float*)p)[i];
}
__device__ __forceinline__ void gstore(void* p, size_t i, bool bf, float v) {
    if (bf) ((bf16*)p)[i] = __float2bfloat16(v);
    else    ((float*)p)[i] = v;
}

// direct global->LDS, 16 bytes/lane. LDS base must be wave-uniform (m104);
// lane writes at base + lane*16. Global address is per-lane.
__device__ __forceinline__ void async16(const bf16* g, const bf16* l) {
    __builtin_amdgcn_global_load_lds(
        (const __attribute__((address_space(1))) void*)g,
        (__attribute__((address_space(3))) void*)l, 16, 0, 0);
}

// ---- dtype probe (64 lanes, ballot) ---------------------------------------
__global__ void detect_kernel(const void* __restrict__ probe) {
    const int lane = threadIdx.x & 63;
    const bf16* h = (const bf16*)probe;
    int ok = 1;
    #pragma unroll
    for (int j = 0; j < 4; ++j) {
        float v = __bfloat162float(h[lane * 4 + j]);
        if (!(fabsf(v) <= 1000.0f)) ok = 0;   // catches huge AND NaN
    }
    unsigned long long m = __ballot(ok);
    if (lane == 0)
        __hip_atomic_store(&g_is_bf16, m == ~0ull ? 1 : 0, __ATOMIC_RELEASE,
                           __HIP_MEMORY_SCOPE_AGENT);
}

// ---- weight arena offsets (bf16 elems) — fp32-input path only -------------
#define O_W1  0ull
#define O_W2  2097152ull
#define O_QK  4194304ull
#define O_WV  8388608ull
#define O_WO  10485760ull
#define O_F1  12582912ull
#define O_F2  13107200ull
#define ARENA_ELEMS 13631488ull

// one block = 16384 elems; per iteration a wave does unit-stride float4
// reads (1KB/instr) and unit-stride uint2 bf16 writes (512B/instr).
__global__ __launch_bounds__(256) void cvt_weights(
        const void* W1, const void* W2, const void* Wq, const void* Wk,
        const void* Wv, const void* Wo, const void* F1, const void* F2,
        bf16* __restrict__ arena) {
    if (flagbf_block()) return;   // bf16 inputs: GEMMs read them directly
    int b = blockIdx.x;
    const float* src; bf16* dst;
    if      (b < 128)  {           src = (const float*)W1 + (size_t)b * 16384;
                         dst = arena + O_W1 + (size_t)b * 16384; }
    else if (b < 256)  { b -= 128; src = (const float*)W2 + (size_t)b * 16384;
                         dst = arena + O_W2 + (size_t)b * 16384; }
    else if (b < 384)  { b -= 256; src = (const float*)Wq + (size_t)b * 16384;
                         dst = arena + O_QK + (size_t)(b >> 6) * 2097152
                                            + (size_t)(b & 63) * 16384; }
    else if (b < 512)  { b -= 384; src = (const float*)Wk + (size_t)b * 16384;
                         dst = arena + O_QK + (size_t)(b >> 6) * 2097152
                                            + 1048576 + (size_t)(b & 63) * 16384; }
    else if (b < 640)  { b -= 512; src = (const float*)Wv + (size_t)b * 16384;
                         dst = arena + O_WV + (size_t)b * 16384; }
    else if (b < 768)  { b -= 640; src = (const float*)Wo + (size_t)b * 16384;
                         dst = arena + O_WO + (size_t)b * 16384; }
    else if (b < 800)  { b -= 768; src = (const float*)F1 + (size_t)b * 16384;
                         dst = arena + O_F1 + (size_t)b * 16384; }
    else               { b -= 800; src = (const float*)F2 + (size_t)b * 16384;
                         dst = arena + O_F2 + (size_t)b * 16384; }
    const int tid = threadIdx.x;
    #pragma unroll
    for (int it = 0; it < 16; ++it) {
        const int e = it * 1024 + tid * 4;
        float4 f = *(const float4*)(src + e);
        bf16 t[4] = {__float2bfloat16(f.x), __float2bfloat16(f.y),
                     __float2bfloat16(f.z), __float2bfloat16(f.w)};
        *(uint2*)(dst + e) = *(const uint2*)t;
    }
}

__global__ __launch_bounds__(256) void cvt_x(
        const void* __restrict__ X, size_t x_off, bf16* __restrict__ dst) {
    if (flagbf_block()) return;   // bf16 x is consumed in place
    const float* src = (const float*)X + x_off + (size_t)blockIdx.x * 16384;
    bf16* d = dst + (size_t)blockIdx.x * 16384;
    const int tid = threadIdx.x;
    #pragma unroll
    for (int it = 0; it < 16; ++it) {
        const int e = it * 1024 + tid * 4;
        float4 f = *(const float4*)(src + e);
        bf16 t[4] = {__float2bfloat16(f.x), __float2bfloat16(f.y),
                     __float2bfloat16(f.z), __float2bfloat16(f.w)};
        *(uint2*)(d + e) = *(const uint2*)t;
    }
}

// ---------------- m97-structure GEMM: C[M,N] = op(A[M,K] @ W[N,K]^T + b) ---
// Operand pointers come in (bf16-direct, converted-arena) pairs, selected on
// the device dtype flag; all row offsets folded host-side.
// CMODE: 0 = bf16 scratch C, 1 = flag-dtype harness buffer.
// TRANSC: store C^T (bf16) at C[col*M + row] — used to produce V^T.
// BIAS2: two-way weight/bias select at col 1024 (merged QK GEMM, uniform).
// XCD bm-band swizzle: each XCD gets a contiguous band of bm rows.
template <bool RELU, bool ADD, int CMODE, bool TRANSC, bool BIAS2>
__global__ __launch_bounds__(256) void gemm_bf16(
        const bf16* Abf, const bf16* Acv,
        const bf16* Wlo_bf, const bf16* Whi_bf,
        const bf16* Wlo_cv, const bf16* Whi_cv,
        const void* __restrict__ bias, const void* __restrict__ bias2,
        size_t b_off,
        void* __restrict__ C, size_t c_off,
        int M, int N, int K) {
    const bool fl = flagbf_block();
    const bf16* A   = fl ? Abf : Acv;
    const bf16* Wlo = fl ? Wlo_bf : Wlo_cv;
    const bf16* Whi = fl ? Whi_bf : Whi_cv;

    __shared__ __align__(16) bf16 As[128 * 64];
    __shared__ __align__(16) bf16 Bs[128 * 64];

    // XCD bm-band remap (bijective; gridDim.y always divisible by 8 here:
    // gy = Mc/128 in {8,16,32,64}). lin%8 tracks dispatch->XCD round-robin.
    const int gx = gridDim.x;
    const int lin = blockIdx.x + gx * blockIdx.y;
    const int xcd = lin & 7, j = lin >> 3;
    const int rpx = gridDim.y >> 3;           // bm rows per XCD band
    const int bm = (xcd * rpx + j / gx) * 128;
    const int bn = (j % gx) * 128;

    const int tid = threadIdx.x;
    const int wave = tid >> 6, lane = tid & 63;
    const int quad = lane >> 4, l15 = lane & 15;
    const int wr = wave >> 1, wc = wave & 1;
    const int l8 = lane >> 3, l7 = lane & 7;
    const int swz = l7 ^ l8;          // row&7 == l8 for our staging rows

    const bf16* Wp;
    int bnr;
    if (BIAS2 && bn >= 1024) { Wp = Whi; bnr = bn - 1024; }
    else                     { Wp = Wlo; bnr = bn; }

    f32x4 acc[4][4];
    #pragma unroll
    for (int i = 0; i < 4; ++i)
        #pragma unroll
        for (int j2 = 0; j2 < 4; ++j2) acc[i][j2] = (f32x4){0.f, 0.f, 0.f, 0.f};

    // wave w stages rows [w*32, w*32+32) of both tiles; 4 issues of 8 rows.
    const bf16* ga0 = A  + (size_t)(bm  + wave * 32 + l8) * K + swz * 8;
    const bf16* gb0 = Wp + (size_t)(bnr + wave * 32 + l8) * K + swz * 8;
    bf16* la0 = &As[(wave * 32) * 64];
    bf16* lb0 = &Bs[(wave * 32) * 64];

    for (int k0 = 0; k0 < K; k0 += 64) {
        __syncthreads();                       // prev iter frag reads done
        #pragma unroll
        for (int i = 0; i < 4; ++i) {
            async16(ga0 + (size_t)(i * 8) * K + k0, la0 + i * 512);
            async16(gb0 + (size_t)(i * 8) * K + k0, lb0 + i * 512);
        }
        __syncthreads();                       // vmcnt drained by compiler

        #pragma unroll
        for (int ks = 0; ks < 2; ++ks) {
            bf16x8 af[4], bfr[4];
            #pragma unroll
            for (int mi = 0; mi < 4; ++mi) {
                const int row = wr * 64 + mi * 16 + l15;
                af[mi] = *(const bf16x8*)
                    &As[row * 64 + ((((ks << 2) | quad) ^ (row & 7)) << 3)];
            }
            #pragma unroll
            for (int ni = 0; ni < 4; ++ni) {
                const int row = wc * 64 + ni * 16 + l15;
                bfr[ni] = *(const bf16x8*)
                    &Bs[row * 64 + ((((ks << 2) | quad) ^ (row & 7)) << 3)];
            }
            #pragma unroll
            for (int mi = 0; mi < 4; ++mi)
                #pragma unroll
                for (int ni = 0; ni < 4; ++ni)
                    acc[mi][ni] = MFMA16(af[mi], bfr[ni], acc[mi][ni]);
        }
    }

    // epilogue: acc row = quad*4+rr, col = lane&15 (verified m89/m91 layout)
    const bool cbf = CMODE ? fl : true;
    #pragma unroll
    for (int ni = 0; ni < 4; ++ni) {
        const int col = bn + wc * 64 + ni * 16 + l15;
        float bv;
        if (BIAS2) bv = col < 1024 ? gload(bias, b_off + col, fl)
                                   : gload(bias2, b_off + col - 1024, fl);
        else       bv = gload(bias, b_off + col, fl);
        #pragma unroll
        for (int mi = 0; mi < 4; ++mi) {
            const int row0 = bm + wr * 64 + mi * 16 + quad * 4;
            if (TRANSC) {
                bf16 pk[4];
                #pragma unroll
                for (int rr = 0; rr < 4; ++rr)
                    pk[rr] = __float2bfloat16(acc[mi][ni][rr] + bv);
                *(uint2*)((bf16*)C + c_off + (size_t)col * M + row0) =
                    *(const uint2*)pk;
            } else {
                #pragma unroll
                for (int rr = 0; rr < 4; ++rr) {
                    float v = acc[mi][ni][rr] + bv;
                    if (RELU) v = fmaxf(v, 0.f);
                    size_t idx = c_off + (size_t)(row0 + rr) * N + col;
                    if (ADD) v += gload(C, idx, cbf);
                    gstore(C, idx, cbf, v);
                }
            }
        }
    }
}

// ---------------- LayerNorm: one wave per row, shuffle-only ----------------
__global__ __launch_bounds__(256) void ln_wave(
        const void* __restrict__ X, size_t x_off,
        const void* __restrict__ g, const void* __restrict__ b, size_t gb_off,
        bf16* __restrict__ H) {
    const bool fl = flagbf_block();
    const int lane = threadIdx.x & 63;
    const int row = blockIdx.x * 4 + (threadIdx.x >> 6);
    const size_t xrow = x_off + (size_t)row * DMODEL;

    float v[16];
    if (fl) {
        const bf16* xp = (const bf16*)X + xrow;
        #pragma unroll
        for (int c = 0; c < 2; ++c) {
            uint4 raw = *(const uint4*)(xp + c * 512 + lane * 8);
            const bf16* rb = (const bf16*)&raw;
            #pragma unroll
            for (int j = 0; j < 8; ++j) v[c * 8 + j] = __bfloat162float(rb[j]);
        }
    } else {
        const float* xp = (const float*)X + xrow;
        #pragma unroll
        for (int c = 0; c < 4; ++c) {
            float4 f = *(const float4*)(xp + c * 256 + lane * 4);
            v[c * 4 + 0] = f.x; v[c * 4 + 1] = f.y;
            v[c * 4 + 2] = f.z; v[c * 4 + 3] = f.w;
        }
    }

    float s = 0.f;
    #pragma unroll
    for (int j = 0; j < 16; ++j) s += v[j];
    #pragma unroll
    for (int off = 32; off > 0; off >>= 1) s += __shfl_xor(s, off);
    const float mean = s * (1.f / DMODEL);

    float vs = 0.f;
    #pragma unroll
    for (int j = 0; j < 16; ++j) { float d = v[j] - mean; vs += d * d; }
    #pragma unroll
    for (int off = 32; off > 0; off >>= 1) vs += __shfl_xor(vs, off);
    const float rstd = rsqrtf(vs * (1.f / DMODEL) + 1e-12f);

    bf16* h = H + (size_t)row * DMODEL;
    if (fl) {
        const bf16* gp = (const bf16*)g + gb_off;
        const bf16* bp = (const bf16*)b + gb_off;
        #pragma unroll
        for (int c = 0; c < 2; ++c) {
            const int o = c * 512 + lane * 8;
            uint4 gr = *(const uint4*)(gp + o);
            uint4 br = *(const uint4*)(bp + o);
            const bf16* gg = (const bf16*)&gr;
            const bf16* bb = (const bf16*)&br;
            bf16 outv[8];
            #pragma unroll
            for (int j = 0; j < 8; ++j)
                outv[j] = __float2bfloat16((v[c * 8 + j] - mean) * rstd *
                          __bfloat162float(gg[j]) + __bfloat162float(bb[j]));
            *(uint4*)(h + o) = *(const uint4*)outv;
        }
    } else {
        const float* gp = (const float*)g + gb_off;
        const float* bp = (const float*)b + gb_off;
        #pragma unroll
        for (int c = 0; c < 4; ++c) {
            const int o = c * 256 + lane * 4;
            float4 gr = *(const float4*)(gp + o);
            float4 br = *(const float4*)(bp + o);
            const float gg[4] = {gr.x, gr.y, gr.z, gr.w};
            const float bb[4] = {br.x, br.y, br.z, br.w};
            bf16 outv[4];
            #pragma unroll
            for (int j = 0; j < 4; ++j)
                outv[j] = __float2bfloat16((v[c * 4 + j] - mean) * rstd * gg[j] + bb[j]);
            *(uint2*)(h + o) = *(const uint2*)outv;
        }
    }
}

// ---------------- Flash-style MFMA attention -------------------------------
// Grid: (TSEQ/128, NHEAD, c). Block: 512 threads = 8 waves, wave w owns
// q-rows [qt*128 + w*16, +16). K loop over 64-key tiles staged in LDS.
// QK: fused [Mc][2048] buffer (Q at col h*128, K at col 1024+h*128).
// Vg: V^T [1024][Mc] — staging is vectorized row loads (no transpose).
// XCD swizzle: each XCD owns whole (bb, all-head) groups — the 8 qt-blocks
// sharing K/V (and the 8 heads sharing QK cache lines) stay on one L2.
__global__ __launch_bounds__(512) void attn_mfma(
        const bf16* __restrict__ QK, const bf16* __restrict__ Vg,
        bf16* __restrict__ Om) {
    const int cch = (int)gridDim.z;                  // chunk count c
    const int lin = blockIdx.x + (int)gridDim.x *
                    (blockIdx.y + (int)gridDim.y * blockIdx.z);
    const int xcd = lin & 7, j = lin >> 3;           // 64c blocks, div by 8
    const int qt = j & 7, gl = j >> 3;               // gl in [0,c)
    const int g = xcd * cch + gl;                    // (h,bb) group id
    const int h = g & 7, bb = g >> 3;

    const int Mc = cch * TSEQ;
    const int tid = threadIdx.x;
    const int wave = tid >> 6, lane = tid & 63;
    const int quad = lane >> 4, l15 = lane & 15;

    __shared__ __align__(16) bf16 Kt[64][128];
    __shared__ __align__(16) bf16 Vt[128][64];
    __shared__ __align__(16) bf16 Ps[8][16][72];

    const int qrow = qt * 128 + wave * 16 + l15;
    const float scale = 0.08838834764831845f;  // 1/sqrt(128)

    bf16x8 qf[4];
    #pragma unroll
    for (int kc = 0; kc < 4; ++kc) {
        uint4 raw = *(const uint4*)(QK + (size_t)(bb * TSEQ + qrow) * 2048 +
                                    h * DKH + kc * 32 + quad * 8);
        const bf16* rb = (const bf16*)&raw;
        bf16 tmp[8];
        #pragma unroll
        for (int j2 = 0; j2 < 8; ++j2)
            tmp[j2] = __float2bfloat16(__bfloat162float(rb[j2]) * scale);
        qf[kc] = *(const bf16x8*)tmp;
    }

    f32x4 o[8];
    #pragma unroll
    for (int i = 0; i < 8; ++i) o[i] = (f32x4){0.f, 0.f, 0.f, 0.f};
    float m_i[4] = {-1e30f, -1e30f, -1e30f, -1e30f};
    float l_i[4] = {0.f, 0.f, 0.f, 0.f};

    const int skey = tid >> 3;              // K staging: row = key (0..63)
    const int dseg = (tid & 7) * 16;        // 2 x uint4 per thread
    const int sk7 = skey & 7;
    const int vd = tid >> 2;                // V staging: row = d (0..127)
    const int vseg = (tid & 3) * 16;        // 2 x uint4 per thread

    for (int kt = 0; kt < TSEQ / 64; ++kt) {
        __syncthreads();
        {
            const bf16* kp = QK + (size_t)(bb * TSEQ + kt * 64 + skey) * 2048 +
                             1024 + h * DKH + dseg;
            const bf16* vp = Vg + (size_t)(h * DKH + vd) * Mc + bb * TSEQ +
                             kt * 64 + vseg;
            uint4 kv[2], vv[2];
            #pragma unroll
            for (int g2 = 0; g2 < 2; ++g2) { kv[g2] = ((const uint4*)kp)[g2]; vv[g2] = ((const uint4*)vp)[g2]; }
            #pragma unroll
            for (int g2 = 0; g2 < 2; ++g2) {
                int c = (dseg >> 3) + g2;
                *(uint4*)&Kt[skey][(c ^ sk7) << 3] = kv[g2];
            }
            #pragma unroll
            for (int g2 = 0; g2 < 2; ++g2) {
                int c = (vseg >> 3) + g2;
                *(uint4*)&Vt[vd][(c ^ (vd & 7)) << 3] = vv[g2];
            }
        }
        __syncthreads();

        f32x4 s[4];
        #pragma unroll
        for (int ni = 0; ni < 4; ++ni) s[ni] = (f32x4){0.f, 0.f, 0.f, 0.f};
        #pragma unroll
        for (int ni = 0; ni < 4; ++ni) {
            const int key = ni * 16 + l15;
            #pragma unroll
            for (int kc = 0; kc < 4; ++kc) {
                const int d3 = kc * 4 + quad;
                bf16x8 kb = *(const bf16x8*)&Kt[key][(d3 ^ (key & 7)) << 3];
                s[ni] = MFMA16(qf[kc], kb, s[ni]);
            }
        }

        float tm[4], ts[4];
        #pragma unroll
        for (int rr = 0; rr < 4; ++rr) {
            float v = fmaxf(fmaxf(s[0][rr], s[1][rr]), fmaxf(s[2][rr], s[3][rr]));
            v = fmaxf(v, __shfl_xor(v, 1));
            v = fmaxf(v, __shfl_xor(v, 2));
            v = fmaxf(v, __shfl_xor(v, 4));
            v = fmaxf(v, __shfl_xor(v, 8));
            tm[rr] = v;
        }
        // T13: only rescale when the running max grows by > 8 (wave-uniform)
        int grow = 0;
        #pragma unroll
        for (int rr = 0; rr < 4; ++rr)
            grow |= (tm[rr] > m_i[rr] + 8.f) ? 1 : 0;
        if (__any(grow)) {
            float al[4];
            #pragma unroll
            for (int rr = 0; rr < 4; ++rr) {
                float mn = fmaxf(m_i[rr], tm[rr]);
                al[rr] = __expf(m_i[rr] - mn);
                m_i[rr] = mn;
                l_i[rr] *= al[rr];
            }
            #pragma unroll
            for (int i = 0; i < 8; ++i)
                #pragma unroll
                for (int rr = 0; rr < 4; ++rr) o[i][rr] *= al[rr];
        }
        #pragma unroll
        for (int rr = 0; rr < 4; ++rr) ts[rr] = 0.f;
        #pragma unroll
        for (int ni = 0; ni < 4; ++ni)
            #pragma unroll
            for (int rr = 0; rr < 4; ++rr) {
                float p = __expf(s[ni][rr] - m_i[rr]);
                s[ni][rr] = p;
                ts[rr] += p;
            }
        #pragma unroll
        for (int rr = 0; rr < 4; ++rr) {
            float v = ts[rr];
            v += __shfl_xor(v, 1);
            v += __shfl_xor(v, 2);
            v += __shfl_xor(v, 4);
            v += __shfl_xor(v, 8);
            l_i[rr] += v;
        }

        #pragma unroll
        for (int ni = 0; ni < 4; ++ni)
            #pragma unroll
            for (int rr = 0; rr < 4; ++rr)
                Ps[wave][quad * 4 + rr][ni * 16 + l15] = __float2bfloat16(s[ni][rr]);
        __asm__ __volatile__("s_waitcnt lgkmcnt(0)" ::: "memory");
        bf16x8 pa[2];
        #pragma unroll
        for (int kc2 = 0; kc2 < 2; ++kc2)
            pa[kc2] = *(const bf16x8*)&Ps[wave][l15][kc2 * 32 + quad * 8];

        #pragma unroll
        for (int ni2 = 0; ni2 < 8; ++ni2) {
            const int d = ni2 * 16 + l15;
            #pragma unroll
            for (int kc2 = 0; kc2 < 2; ++kc2) {
                const int key3 = kc2 * 4 + quad;
                bf16x8 vb = *(const bf16x8*)&Vt[d][(key3 ^ (d & 7)) << 3];
                o[ni2] = MFMA16(pa[kc2], vb, o[ni2]);
            }
        }
    }

    float rinv[4];
    #pragma unroll
    for (int rr = 0; rr < 4; ++rr) rinv[rr] = 1.0f / l_i[rr];
    const size_t obase = (size_t)bb * TSEQ * DMODEL + (size_t)h * DKH;
    #pragma unroll
    for (int ni2 = 0; ni2 < 8; ++ni2)
        #pragma unroll
        for (int rr = 0; rr < 4; ++rr) {
            int qr = qt * 128 + wave * 16 + quad * 4 + rr;
            Om[obase + (size_t)qr * DMODEL + ni2 * 16 + l15] =
                __float2bfloat16(o[ni2][rr] * rinv[rr]);
        }
}

// ---------------------------------------------------------------------------
extern "C" void kernel_launch(void* const* d_in, const int* in_sizes, int n_in,
                              void* d_out, int out_size, void* d_ws, size_t ws_size,
                              hipStream_t stream) {
    const void* x     = d_in[0];
    const void* W1    = d_in[1];
    const void* b1    = d_in[2];
    const void* W2    = d_in[3];
    const void* b2    = d_in[4];
    const void* ln1_g = d_in[5];
    const void* ln1_b = d_in[6];
    const void* ln2_g = d_in[7];
    const void* ln2_b = d_in[8];
    const void* Wq    = d_in[9];
    const void* bq    = d_in[10];
    const void* Wk    = d_in[11];
    const void* bk    = d_in[12];
    const void* Wv    = d_in[13];
    const void* bv    = d_in[14];
    const void* Wo    = d_in[15];
    const void* bo    = d_in[16];
    const void* Fw1   = d_in[17];
    const void* Fb1   = d_in[18];
    const void* Fw2   = d_in[19];
    const void* Fb2   = d_in[20];

    detect_kernel<<<1, 64, 0, stream>>>(W1);

    // workspace: [Hh | QKb | Vtb | Xc | weight arena], all bf16
    int c = 8;
    while (c > 1 &&
           (5ull * (size_t)c * (1ull << 20) + ARENA_ELEMS) * 2ull > ws_size)
        c >>= 1;
    const int nch = 8 / c;
    const int Mc = c * TSEQ;
    const size_t SL = (size_t)Mc * DMODEL;

    bf16* Hh  = (bf16*)d_ws;      // Mc x 1024
    bf16* QKb = Hh + SL;          // Mc x 2048 (fused Q|K)
    bf16* Vtb = QKb + 2 * SL;     // 1024 x Mc (V^T)
    bf16* Xc  = Vtb + SL;         // Mc x 1024 (fp32-input path only)
    bf16* Wt  = Xc + SL;          // weight arena (fp32-input path only)
    bf16* Hid = QKb;              // Mc x 2048 scratch (downsample hidden)
    bf16* Ffh = QKb;              // Mc x 256 scratch (FFN hidden)
    bf16* Ob  = Hh;               // attn output reuses LN buffer
    void* X = d_out;              // residual stream (flag dtype)

    const bf16* xb  = (const bf16*)x;
    bf16* cW1  = Wt + O_W1;
    bf16* cW2  = Wt + O_W2;
    bf16* cWqk = Wt + O_QK;
    bf16* cWv  = Wt + O_WV;
    bf16* cWo  = Wt + O_WO;
    bf16* cF1  = Wt + O_F1;
    bf16* cF2  = Wt + O_F2;

    cvt_weights<<<832, 256, 0, stream>>>(W1, W2, Wq, Wk, Wv, Wo, Fw1, Fw2, Wt);

    for (int ci = 0; ci < nch; ++ci) {
        const size_t roff = (size_t)ci * Mc * DMODEL;

        cvt_x<<<(int)(SL / 16384), 256, 0, stream>>>(x, roff, Xc);

        gemm_bf16<true, false, 0, false, false><<<dim3(DFF / 128, Mc / 128), 256, 0, stream>>>(
            xb + roff, Xc, (const bf16*)W1, (const bf16*)W1, cW1, cW1,
            b1, nullptr, 0, Hid, 0, Mc, DFF, DMODEL);
        gemm_bf16<false, false, 1, false, false><<<dim3(DMODEL / 128, Mc / 128), 256, 0, stream>>>(
            Hid, Hid, (const bf16*)W2, (const bf16*)W2, cW2, cW2,
            b2, nullptr, 0, X, roff, Mc, DMODEL, DFF);

        for (int l = 0; l < 2; ++l) {
            const size_t wOff   = (size_t)l * DMODEL * DMODEL;       // 1M
            const size_t fOff   = (size_t)l * FHID * DMODEL;         // 256K
            const size_t vOff   = (size_t)l * DMODEL;
            const size_t f1bOff = (size_t)l * FHID;

            const bf16* wqL = (const bf16*)Wq + wOff;
            const bf16* wkL = (const bf16*)Wk + wOff;
            const bf16* wvL = (const bf16*)Wv + wOff;
            const bf16* woL = (const bf16*)Wo + wOff;
            const bf16* f1L = (const bf16*)Fw1 + fOff;
            const bf16* f2L = (const bf16*)Fw2 + fOff;
            const bf16* qkLo = cWqk + (size_t)l * 2097152;
            const bf16* qkHi = qkLo + 1048576;

            ln_wave<<<Mc / 4, 256, 0, stream>>>(X, roff, ln1_g, ln1_b, vOff, Hh);
            // fused Q|K GEMM: N=2048, weight/bias select at col 1024 (uniform)
            gemm_bf16<false, false, 0, false, true><<<dim3(2048 / 128, Mc / 128), 256, 0, stream>>>(
                Hh, Hh, wqL, wkL, qkLo, qkHi,
                bq, bk, vOff, QKb, 0, Mc, 2048, DMODEL);
            // V GEMM with transposed store -> Vtb = V^T [1024][Mc]
            gemm_bf16<false, false, 0, true, false><<<dim3(DMODEL / 128, Mc / 128), 256, 0, stream>>>(
                Hh, Hh, wvL, wvL, cWv + wOff, cWv + wOff,
                bv, nullptr, vOff, Vtb, 0, Mc, DMODEL, DMODEL);

            attn_mfma<<<dim3(TSEQ / 128, NHEAD, c), 512, 0, stream>>>(QKb, Vtb, Ob);

            gemm_bf16<false, true, 1, false, false><<<dim3(DMODEL / 128, Mc / 128), 256, 0, stream>>>(
                Ob, Ob, woL, woL, cWo + wOff, cWo + wOff,
                bo, nullptr, vOff, X, roff, Mc, DMODEL, DMODEL);

            ln_wave<<<Mc / 4, 256, 0, stream>>>(X, roff, ln2_g, ln2_b, vOff, Hh);
            gemm_bf16<true, false, 0, false, false><<<dim3(FHID / 128, Mc / 128), 256, 0, stream>>>(
                Hh, Hh, f1L, f1L, cF1 + fOff, cF1 + fOff,
                Fb1, nullptr, f1bOff, Ffh, 0, Mc, FHID, DMODEL);
            gemm_bf16<false, true, 1, false, false><<<dim3(DMODEL / 128, Mc / 128), 256, 0, stream>>>(
                Ffh, Ffh, f2L, f2L, cF2 + fOff, cF2 + fOff,
                Fb2, nullptr, vOff, X, roff, Mc, DMODEL, FHID);
        }
    }
}